// Round 10
// baseline (159.949 us; speedup 1.0000x reference)
//
#include <hip/hip_runtime.h>
#include <hip/hip_bf16.h>
#include <stdint.h>

typedef __attribute__((ext_vector_type(8))) short bf16x8;
typedef __attribute__((ext_vector_type(4))) float f32x4;

__device__ __forceinline__ float bf2f(unsigned short u) {
    union { unsigned int i; float f; } z; z.i = ((unsigned int)u) << 16; return z.f;
}
__device__ __forceinline__ unsigned short f2bf(float f) {
    union { float f; unsigned int i; } z; z.f = f;
    unsigned int x = z.i;
    unsigned int r = x + 0x7fffu + ((x >> 16) & 1u);
    return (unsigned short)(r >> 16);
}

typedef const __attribute__((address_space(1))) unsigned int* gp_t;
typedef __attribute__((address_space(3))) unsigned int* lp_t;

__device__ __forceinline__ void gload_lds16(const void* g, void* l) {
    __builtin_amdgcn_global_load_lds((gp_t)g, (lp_t)l, 16, 0, 0);
}

// bijective XCD-aware remap (m204 form) on a linear block id
__device__ __forceinline__ int xcd_remap(int orig, int nwg) {
    const int q = nwg >> 3, r = nwg & 7;
    const int xcd = orig & 7, pos = orig >> 3;
    return (xcd < r ? xcd * (q + 1) : r * (q + 1) + (xcd - r) * q) + pos;
}

// ---------------- fp32 -> bf16 conversion ----------------
__global__ __launch_bounds__(256) void cvt_x(const float* __restrict__ in,
                                             unsigned short* __restrict__ out, int n4) {
    int i = blockIdx.x * 256 + threadIdx.x;
    int stride = gridDim.x * 256;
    for (; i < n4; i += stride) {
        float4 v = reinterpret_cast<const float4*>(in)[i];
        ushort4 u;
        u.x = f2bf(v.x); u.y = f2bf(v.y); u.z = f2bf(v.z); u.w = f2bf(v.w);
        reinterpret_cast<ushort4*>(out)[i] = u;
    }
}

// weights: z selects {Wq (scaled 1/32), Wk, Wv} -> wqkv + z*DD
__global__ __launch_bounds__(256) void cvt_w(const float* __restrict__ wq,
                                             const float* __restrict__ wk,
                                             const float* __restrict__ wv,
                                             unsigned short* __restrict__ out, int n4) {
    const int z = blockIdx.z;
    const float* in = (z == 0) ? wq : (z == 1) ? wk : wv;
    const float scale = (z == 0) ? 0.03125f : 1.0f;
    unsigned short* o = out + (size_t)z * n4 * 4;
    int i = blockIdx.x * 256 + threadIdx.x;
    int stride = gridDim.x * 256;
    for (; i < n4; i += stride) {
        float4 v = reinterpret_cast<const float4*>(in)[i];
        ushort4 u;
        u.x = f2bf(v.x * scale); u.y = f2bf(v.y * scale);
        u.z = f2bf(v.z * scale); u.w = f2bf(v.w * scale);
        reinterpret_cast<ushort4*>(o)[i] = u;
    }
}

#define MFMA(a, b, c) __builtin_amdgcn_mfma_f32_16x16x32_bf16(a, b, c, 0, 0, 0)
#define SB() __builtin_amdgcn_sched_barrier(0)
#define BAR() __builtin_amdgcn_s_barrier()
#define LGKM0() asm volatile("s_waitcnt lgkmcnt(0)" ::: "memory")

// ======== 256x256 4-phase pipelined NT GEMM core (K=1024, lda=ldb=1024) ====
__device__ __forceinline__ void gemm256_core(
    const unsigned short* __restrict__ Ab,
    const unsigned short* __restrict__ Bb,
    int m0, int n0,
    unsigned short (&As)[2][256 * 64], unsigned short (&Bs)[2][256 * 64],
    f32x4 (&acc)[8][4])
{
    constexpr int LD = 1024, NK = 16;
    const int tid = threadIdx.x;
    const int l = tid & 63, w = tid >> 6;
    const int wr = w >> 2, wc = w & 3;

    const int srow = w * 8 + (l >> 3);
    const int scol = ((l & 7) ^ (l >> 3)) * 8;
    const size_t ldst = (size_t)w * 1024 + (size_t)l * 16;

    auto stageA = [&](int t, int h, int b) {
        const unsigned short* src = Ab + (size_t)(m0 + h * 128 + srow) * LD + t * 64 + scol;
        char* dst = (char*)&As[b][0] + h * 16384 + ldst;
        gload_lds16(src, dst);
        gload_lds16(src + (size_t)64 * LD, dst + 8192);
    };
    auto stageB = [&](int t, int h, int b) {
        const unsigned short* src = Bb + (size_t)(n0 + h * 128 + srow) * LD + t * 64 + scol;
        char* dst = (char*)&Bs[b][0] + h * 16384 + ldst;
        gload_lds16(src, dst);
        gload_lds16(src + (size_t)64 * LD, dst + 8192);
    };

    const int l15 = l & 15, l7 = l & 7;
    const int s0 = (((l >> 4) ^ l7) * 16);
    const int s1 = ((((l >> 4) + 4) ^ l7) * 16);

    bf16x8 Af[4][2], Bf0[2][2], Bf1[2][2];

    stageA(0, 0, 0); stageA(0, 1, 0); stageB(0, 0, 0); stageB(0, 1, 0);
    stageB(1, 0, 1); stageB(1, 1, 1);
    asm volatile("s_waitcnt vmcnt(4)" ::: "memory");
    SB(); BAR(); SB();

    for (int t = 0; t < NK; ++t) {
        const int b = t & 1, bn = b ^ 1;
        const char* ab = (const char*)&As[b][0] + (wr * 128 + l15) * 128;
        const char* bb = (const char*)&Bs[b][0] + (wc * 64 + l15) * 128;

        // P1: Q(0,0); stage A0(t+1)
        #pragma unroll
        for (int mi = 0; mi < 4; ++mi) {
            Af[mi][0] = *(const bf16x8*)(ab + mi * 2048 + s0);
            Af[mi][1] = *(const bf16x8*)(ab + mi * 2048 + s1);
        }
        #pragma unroll
        for (int ni = 0; ni < 2; ++ni) {
            Bf0[ni][0] = *(const bf16x8*)(bb + ni * 2048 + s0);
            Bf0[ni][1] = *(const bf16x8*)(bb + ni * 2048 + s1);
        }
        if (t + 1 < NK) stageA(t + 1, 0, bn);
        BAR(); LGKM0(); SB();
        __builtin_amdgcn_s_setprio(1);
        #pragma unroll
        for (int mi = 0; mi < 4; ++mi)
            #pragma unroll
            for (int ni = 0; ni < 2; ++ni) {
                acc[mi][ni] = MFMA(Af[mi][0], Bf0[ni][0], acc[mi][ni]);
                acc[mi][ni] = MFMA(Af[mi][1], Bf0[ni][1], acc[mi][ni]);
            }
        __builtin_amdgcn_s_setprio(0);
        SB(); BAR(); SB();

        // P2: Q(0,1); stage A1(t+1)
        #pragma unroll
        for (int ni = 0; ni < 2; ++ni) {
            Bf1[ni][0] = *(const bf16x8*)(bb + 4096 + ni * 2048 + s0);
            Bf1[ni][1] = *(const bf16x8*)(bb + 4096 + ni * 2048 + s1);
        }
        if (t + 1 < NK) stageA(t + 1, 1, bn);
        BAR(); LGKM0(); SB();
        __builtin_amdgcn_s_setprio(1);
        #pragma unroll
        for (int mi = 0; mi < 4; ++mi)
            #pragma unroll
            for (int ni = 0; ni < 2; ++ni) {
                acc[mi][2 + ni] = MFMA(Af[mi][0], Bf1[ni][0], acc[mi][2 + ni]);
                acc[mi][2 + ni] = MFMA(Af[mi][1], Bf1[ni][1], acc[mi][2 + ni]);
            }
        __builtin_amdgcn_s_setprio(0);
        SB(); BAR(); SB();

        // P3: Q(1,1); reads A qm1; stage B0(t+2) into b
        #pragma unroll
        for (int mi = 0; mi < 4; ++mi) {
            Af[mi][0] = *(const bf16x8*)(ab + 8192 + mi * 2048 + s0);
            Af[mi][1] = *(const bf16x8*)(ab + 8192 + mi * 2048 + s1);
        }
        if (t + 2 < NK) stageB(t + 2, 0, b);
        BAR(); LGKM0(); SB();
        __builtin_amdgcn_s_setprio(1);
        #pragma unroll
        for (int mi = 0; mi < 4; ++mi)
            #pragma unroll
            for (int ni = 0; ni < 2; ++ni) {
                acc[4 + mi][2 + ni] = MFMA(Af[mi][0], Bf1[ni][0], acc[4 + mi][2 + ni]);
                acc[4 + mi][2 + ni] = MFMA(Af[mi][1], Bf1[ni][1], acc[4 + mi][2 + ni]);
            }
        __builtin_amdgcn_s_setprio(0);
        SB(); BAR(); SB();

        // P4: Q(1,0); no reads; stage B1(t+2)
        if (t + 2 < NK) stageB(t + 2, 1, b);
        BAR(); SB();
        __builtin_amdgcn_s_setprio(1);
        #pragma unroll
        for (int mi = 0; mi < 4; ++mi)
            #pragma unroll
            for (int ni = 0; ni < 2; ++ni) {
                acc[4 + mi][ni] = MFMA(Af[mi][0], Bf0[ni][0], acc[4 + mi][ni]);
                acc[4 + mi][ni] = MFMA(Af[mi][1], Bf0[ni][1], acc[4 + mi][ni]);
            }
        __builtin_amdgcn_s_setprio(0);
        if (t + 2 < NK) {
            asm volatile("s_waitcnt vmcnt(4)" ::: "memory");
        } else if (t + 1 < NK) {
            asm volatile("s_waitcnt vmcnt(0)" ::: "memory");
        }
        SB(); BAR(); SB();
    }
}

// ======== d1: Q+K projection. 256 blocks (32 x 8), exact 1 round ======
__global__ __launch_bounds__(512, 2) void qk_proj(
    const unsigned short* __restrict__ xb, const unsigned short* __restrict__ wqkv,
    unsigned short* __restrict__ qb, unsigned short* __restrict__ kb)
{
    const int wg = xcd_remap(blockIdx.x, 256);
    const int mt = wg & 31, nt = wg >> 5;      // nt 0..7
    const int m0 = mt * 256, n0 = nt * 256;

    __shared__ unsigned short As[2][256 * 64];
    __shared__ unsigned short Bs[2][256 * 64];
    f32x4 acc[8][4] = {};

    gemm256_core(xb, wqkv, m0, n0, As, Bs, acc);

    const int tid = threadIdx.x;
    const int l = tid & 63, w = tid >> 6;
    const int wr = w >> 2, wc = w & 3;
    const int crow = (l >> 4) * 4, ccol = l & 15;
    unsigned short* C = (nt < 4) ? qb : kb;
    const int cb = (nt < 4) ? n0 : n0 - 1024;
    #pragma unroll
    for (int mi = 0; mi < 8; ++mi)
        #pragma unroll
        for (int ni = 0; ni < 4; ++ni) {
            const size_t rbase = (size_t)(m0 + wr * 128 + mi * 16 + crow);
            const size_t cg = (size_t)(cb + wc * 64 + ni * 16 + ccol);
            #pragma unroll
            for (int r = 0; r < 4; ++r)
                C[(rbase + r) * 1024 + cg] = f2bf(acc[mi][ni][r]);
        }
}

// ======== 128x128 BK=64 core, counted-vmcnt 2-deep pipeline ========
// 4 waves (2x2), 3-bit XOR swizzle (slot ^= row&7, pre-swizzled source).
// Per K-tile: {16 ds_read b128 -> lgkm0 -> bar (all waves done reading b)
//   -> stage(t+2 -> b) -> prio1 32 MFMA prio0 -> vmcnt(8) [oldest 8 = t+1
//   landed; never drains to 0 mid-loop] -> bar}.
__device__ __forceinline__ void gemm128_core64(
    const unsigned short* __restrict__ Ab, int lda,
    const unsigned short* __restrict__ Bb, int ldb,
    int m0, int n0, int nk,
    unsigned short (&As)[2][128 * 64], unsigned short (&Bs)[2][128 * 64],
    f32x4 (&acc)[4][4])
{
    const int tid = threadIdx.x;
    const int l = tid & 63, w = tid >> 6;
    const int wr = w >> 1, wc = w & 1;
    const int l15 = l & 15;

    const int srow = w * 8 + (l >> 3);
    const int scol = ((l & 7) ^ (l >> 3)) * 8;     // pre-swizzled source col
    const size_t ldst = (size_t)w * 1024 + (size_t)l * 16;

    auto stage = [&](int t, int b) {
        const int k0 = t * 64;
        #pragma unroll
        for (int i = 0; i < 4; ++i) {
            gload_lds16(Ab + (size_t)(m0 + i * 32 + srow) * lda + k0 + scol,
                        (char*)&As[b][0] + i * 4096 + ldst);
            gload_lds16(Bb + (size_t)(n0 + i * 32 + srow) * ldb + k0 + scol,
                        (char*)&Bs[b][0] + i * 4096 + ldst);
        }
    };

    const int s0 = (((l >> 4) ^ (l & 7)) * 16);
    const int s1 = ((((l >> 4) + 4) ^ (l & 7)) * 16);

    // prologue: tiles 0 and 1 in flight; wait oldest 8 (tile 0)
    stage(0, 0);
    if (nk > 1) {
        stage(1, 1);
        asm volatile("s_waitcnt vmcnt(8)" ::: "memory");
    } else {
        asm volatile("s_waitcnt vmcnt(0)" ::: "memory");
    }
    SB(); BAR(); SB();

    for (int t = 0; t < nk; ++t) {
        const int b = t & 1;
        const char* ab = (const char*)&As[b][0] + (wr * 64 + l15) * 128;
        const char* bb = (const char*)&Bs[b][0] + (wc * 64 + l15) * 128;
        bf16x8 af[4][2], bfr[4][2];
        #pragma unroll
        for (int m = 0; m < 4; ++m) {
            af[m][0] = *(const bf16x8*)(ab + m * 2048 + s0);
            af[m][1] = *(const bf16x8*)(ab + m * 2048 + s1);
        }
        #pragma unroll
        for (int n = 0; n < 4; ++n) {
            bfr[n][0] = *(const bf16x8*)(bb + n * 2048 + s0);
            bfr[n][1] = *(const bf16x8*)(bb + n * 2048 + s1);
        }
        LGKM0(); SB();          // own reads in VGPRs (rule 18: SB after waitcnt)
        BAR(); SB();            // ALL waves done reading buffer b
        if (t + 2 < nk) stage(t + 2, b);   // overwrite b, 2 tiles ahead

        __builtin_amdgcn_s_setprio(1);
        #pragma unroll
        for (int m = 0; m < 4; ++m)
            #pragma unroll
            for (int n = 0; n < 4; ++n) {
                acc[m][n] = MFMA(af[m][0], bfr[n][0], acc[m][n]);
                acc[m][n] = MFMA(af[m][1], bfr[n][1], acc[m][n]);
            }
        __builtin_amdgcn_s_setprio(0);

        if (t + 2 < nk) {
            asm volatile("s_waitcnt vmcnt(8)" ::: "memory");   // t+1 landed
        } else if (t + 1 < nk) {
            asm volatile("s_waitcnt vmcnt(0)" ::: "memory");   // final drain
        }
        SB(); BAR(); SB();
    }
}

// ======== d2: V-proj (512 blocks) + causal scores (544 blocks) @128² =======
__global__ __launch_bounds__(256) void v_scores128(
    const unsigned short* __restrict__ xb, const unsigned short* __restrict__ wv,
    const unsigned short* __restrict__ qb, const unsigned short* __restrict__ kb,
    unsigned short* __restrict__ vt, unsigned short* __restrict__ sc)
{
    const int wg = xcd_remap(blockIdx.x, 1056);

    __shared__ unsigned short As[2][128 * 64];
    __shared__ unsigned short Bs[2][128 * 64];
    f32x4 acc[4][4] = {};

    const int tid = threadIdx.x;
    const int l = tid & 63, w = tid >> 6;
    const int wr = w >> 1, wc = w & 1;
    const int crow = (l >> 4) * 4, ccol = l & 15;

    if (wg < 512) {
        // V-projection: x[8192][1024] * Wv^T -> stored transposed Vt[1024][8192]
        const int mt = wg & 63, nt = wg >> 6;   // 64 x 8
        const int m0 = mt * 128, n0 = nt * 128;
        gemm128_core64(xb, 1024, wv, 1024, m0, n0, 16, As, Bs, acc);
        #pragma unroll
        for (int m = 0; m < 4; ++m)
            #pragma unroll
            for (int n = 0; n < 4; ++n) {
                const int rbase = m0 + wr * 64 + m * 16 + crow;
                const int o = n0 + wc * 64 + n * 16 + ccol;
                ushort4 u;
                u.x = f2bf(acc[m][n][0]);
                u.y = f2bf(acc[m][n][1]);
                u.z = f2bf(acc[m][n][2]);
                u.w = f2bf(acc[m][n][3]);
                *reinterpret_cast<ushort4*>(&vt[(size_t)o * 8192 + rbase]) = u;
            }
    } else {
        // scores: per-batch causal 128-tiles, nt <= mt, 136 per batch
        const int s = wg - 512;
        const int z = s / 136, r = s % 136;
        int mt = (int)((__builtin_sqrtf(8.f * r + 1.f) - 1.f) * 0.5f);
        while ((mt + 1) * (mt + 2) / 2 <= r) ++mt;
        while (mt * (mt + 1) / 2 > r) --mt;
        const int nt = r - mt * (mt + 1) / 2;
        const int m0 = mt * 128, n0 = nt * 128;
        const unsigned short* Ab = qb + (size_t)z * 2048 * 1024;
        const unsigned short* Bb = kb + (size_t)z * 2048 * 1024;
        gemm128_core64(Ab, 1024, Bb, 1024, m0, n0, 16, As, Bs, acc);
        unsigned short* C = sc + (size_t)z * 2048 * 2048;
        #pragma unroll
        for (int m = 0; m < 4; ++m)
            #pragma unroll
            for (int n = 0; n < 4; ++n) {
                const size_t rbase = (size_t)(m0 + wr * 64 + m * 16 + crow);
                const size_t cg = (size_t)(n0 + wc * 64 + n * 16 + ccol);
                #pragma unroll
                for (int r2 = 0; r2 < 4; ++r2)
                    C[(rbase + r2) * 2048 + cg] = f2bf(acc[m][n][r2]);
            }
    }
}

// ======== PV GEMM: 128x128 BK=64 core, fp32 out, causal K-limit ========
__global__ __launch_bounds__(256) void gemm128_pv(
    const unsigned short* __restrict__ A, int lda, long long sA,
    const unsigned short* __restrict__ B, int ldb, long long sB,
    float* __restrict__ C, int ldc, long long sC, int K)
{
    const int GX = gridDim.x, GY = gridDim.y;
    const int nwg = GX * GY * gridDim.z;
    const int orig = blockIdx.x + GX * (blockIdx.y + GY * blockIdx.z);
    const int wgid = xcd_remap(orig, nwg);
    const int mt = wgid % GX;
    const int tq = wgid / GX;
    const int nt = tq % GY, z = tq / GY;

    const unsigned short* Ab = A + (size_t)z * sA;
    const unsigned short* Bb = B + (size_t)z * sB;
    const int Keff = ((mt + 1) * 128 < K) ? (mt + 1) * 128 : K;
    const int nk = Keff >> 6;          // Keff multiple of 128 => exact

    __shared__ unsigned short As[2][128 * 64];
    __shared__ unsigned short Bs[2][128 * 64];
    f32x4 acc[4][4] = {};

    gemm128_core64(Ab, lda, Bb, ldb, mt * 128, nt * 128, nk, As, Bs, acc);

    const int tid = threadIdx.x;
    const int l = tid & 63, w = tid >> 6;
    const int wr = w >> 1, wc = w & 1;
    const int crow = (l >> 4) * 4, ccol = l & 15;
    float* Cb = C + (size_t)z * sC;
    #pragma unroll
    for (int m = 0; m < 4; ++m)
        #pragma unroll
        for (int n = 0; n < 4; ++n) {
            const size_t rbase = (size_t)(mt * 128 + wr * 64 + m * 16 + crow);
            const size_t cg = (size_t)(nt * 128 + wc * 64 + n * 16 + ccol);
            #pragma unroll
            for (int r = 0; r < 4; ++r)
                Cb[(rbase + r) * ldc + cg] = acc[m][n][r];
        }
}

// ---------------- causal row softmax, in-place on bf16 scores ----------------
__global__ __launch_bounds__(256) void softmax_causal(unsigned short* __restrict__ P) {
    const int S = 2048;
    const int gq = blockIdx.x;
    const int q = gq & (S - 1);
    unsigned short* row = P + (size_t)gq * S;
    const int t = threadIdx.x;
    const int c0 = t * 8;
    const int l = t & 63, w = t >> 6;
    const int wlim = ((q >> 7) + 1) << 7;
    const float NEG = -__builtin_huge_valf();

    float f[8];
    if (c0 <= q) {
        uint4 rv = *reinterpret_cast<const uint4*>(row + c0);
        unsigned short us[8];
        us[0] = rv.x & 0xffff; us[1] = rv.x >> 16;
        us[2] = rv.y & 0xffff; us[3] = rv.y >> 16;
        us[4] = rv.z & 0xffff; us[5] = rv.z >> 16;
        us[6] = rv.w & 0xffff; us[7] = rv.w >> 16;
        #pragma unroll
        for (int i = 0; i < 8; ++i)
            f[i] = (c0 + i <= q) ? bf2f(us[i]) : NEG;
    } else {
        #pragma unroll
        for (int i = 0; i < 8; ++i) f[i] = NEG;
    }

    float m = f[0];
    #pragma unroll
    for (int i = 1; i < 8; ++i) m = fmaxf(m, f[i]);
    #pragma unroll
    for (int o = 1; o < 64; o <<= 1) m = fmaxf(m, __shfl_xor(m, o));

    __shared__ float smax[4], ssum[4];
    if (l == 0) smax[w] = m;
    __syncthreads();
    m = fmaxf(fmaxf(smax[0], smax[1]), fmaxf(smax[2], smax[3]));

    float e[8];
    float s = 0.f;
    #pragma unroll
    for (int i = 0; i < 8; ++i) {
        e[i] = exp2f((f[i] - m) * 1.44269504f);
        s += e[i];
    }
    #pragma unroll
    for (int o = 1; o < 64; o <<= 1) s += __shfl_xor(s, o);
    if (l == 0) ssum[w] = s;
    __syncthreads();
    s = ssum[0] + ssum[1] + ssum[2] + ssum[3];
    const float inv = 1.0f / s;

    if (c0 < wlim) {
        uint4 ov;
        ov.x = f2bf(e[0] * inv) | ((unsigned int)f2bf(e[1] * inv) << 16);
        ov.y = f2bf(e[2] * inv) | ((unsigned int)f2bf(e[3] * inv) << 16);
        ov.z = f2bf(e[4] * inv) | ((unsigned int)f2bf(e[5] * inv) << 16);
        ov.w = f2bf(e[6] * inv) | ((unsigned int)f2bf(e[7] * inv) << 16);
        *reinterpret_cast<uint4*>(row + c0) = ov;
    }
}

extern "C" void kernel_launch(void* const* d_in, const int* in_sizes, int n_in,
                              void* d_out, int out_size, void* d_ws, size_t ws_size,
                              hipStream_t stream) {
    const float* x  = (const float*)d_in[0];
    const float* Wq = (const float*)d_in[1];
    const float* Wk = (const float*)d_in[2];
    const float* Wv = (const float*)d_in[3];
    float* out = (float*)d_out;

    const int Bz = 4, S = 2048, D = 1024;
    const int MS = Bz * S;       // 8192
    const int DD = D * D;

    char* ws = (char*)d_ws;
    unsigned short* xb   = (unsigned short*)(ws);                      // 16 MB [8192][1024]
    unsigned short* wqkv = (unsigned short*)(ws + (16ull << 20));      //  6 MB [3072][1024]
    unsigned short* qb   = (unsigned short*)(ws + (22ull << 20));      // 16 MB [8192][1024]
    unsigned short* kb   = (unsigned short*)(ws + (38ull << 20));      // 16 MB [8192][1024]
    unsigned short* vt   = (unsigned short*)(ws + (54ull << 20));      // 16 MB [1024][8192] (V^T)
    unsigned short* sc   = (unsigned short*)(ws + (70ull << 20));      // 32 MB [4][2048][2048]

    // 1. bf16 conversion (softmax scale folded into Wq)
    cvt_x<<<2048, 256, 0, stream>>>(x, xb, MS * D / 4);
    cvt_w<<<dim3(512, 1, 3), 256, 0, stream>>>(Wq, Wk, Wv, wqkv, DD / 4);

    // 2. d1: Q,K projection (256 blocks @256², exact machine fill)
    qk_proj<<<256, 512, 0, stream>>>(xb, wqkv, qb, kb);

    // 3. d2: V projection (512) + causal scores (544) @128²/BK=64, 2-deep vmcnt
    v_scores128<<<1056, 256, 0, stream>>>(xb, wqkv + (size_t)2 * DD, qb, kb, vt, sc);

    // 4. causal softmax in place (zero-fills up to the PV read extent)
    softmax_causal<<<MS, 256, 0, stream>>>(sc);

    // 5. out = P * V == P * Vt^T  (128²/BK=64 core, fp32 out, causal K-limit)
    gemm128_pv<<<dim3(S / 128, D / 128, Bz), 256, 0, stream>>>(
        sc, S, (long long)S * S, vt, MS, S, out, D, (long long)S * D, S);
}

// Round 11
// 156.824 us; speedup vs baseline: 1.0199x; 1.0199x over previous
//
#include <hip/hip_runtime.h>
#include <hip/hip_bf16.h>
#include <stdint.h>

typedef __attribute__((ext_vector_type(8))) short bf16x8;
typedef __attribute__((ext_vector_type(4))) float f32x4;

__device__ __forceinline__ float bf2f(unsigned short u) {
    union { unsigned int i; float f; } z; z.i = ((unsigned int)u) << 16; return z.f;
}
__device__ __forceinline__ unsigned short f2bf(float f) {
    union { float f; unsigned int i; } z; z.f = f;
    unsigned int x = z.i;
    unsigned int r = x + 0x7fffu + ((x >> 16) & 1u);
    return (unsigned short)(r >> 16);
}

typedef const __attribute__((address_space(1))) unsigned int* gp_t;
typedef __attribute__((address_space(3))) unsigned int* lp_t;

__device__ __forceinline__ void gload_lds16(const void* g, void* l) {
    __builtin_amdgcn_global_load_lds((gp_t)g, (lp_t)l, 16, 0, 0);
}

// bijective XCD-aware remap (m204 form) on a linear block id
__device__ __forceinline__ int xcd_remap(int orig, int nwg) {
    const int q = nwg >> 3, r = nwg & 7;
    const int xcd = orig & 7, pos = orig >> 3;
    return (xcd < r ? xcd * (q + 1) : r * (q + 1) + (xcd - r) * q) + pos;
}

// ---------------- fused fp32 -> bf16 conversion, one dispatch ----------------
// flat float4 index: [0, NX) -> x->xb ; then 3 x DD4 regions -> Wq,Wk,Wv->wqkv
// (Wq pre-scaled by 1/32). All region boundaries are powers of two.
__global__ __launch_bounds__(256) void cvt_all(
    const float* __restrict__ x, const float* __restrict__ wq,
    const float* __restrict__ wk, const float* __restrict__ wv,
    unsigned short* __restrict__ xb, unsigned short* __restrict__ wqkv) {
    const int NX = 1 << 21;          // 8192*1024/4
    const int DD4 = 1 << 18;         // 1024*1024/4
    const int total = NX + 3 * DD4;
    int i = blockIdx.x * 256 + threadIdx.x;
    const int stride = gridDim.x * 256;
    for (; i < total; i += stride) {
        const float* src;
        ushort4* dst;
        float scale = 1.0f;
        int idx;
        if (i < NX) {
            src = x; dst = (ushort4*)xb; idx = i;
        } else {
            const int j = i - NX;
            const int r = j >> 18;           // 0,1,2
            src = (r == 0) ? wq : (r == 1) ? wk : wv;
            if (r == 0) scale = 0.03125f;
            dst = (ushort4*)wqkv + (size_t)r * DD4;
            idx = j & (DD4 - 1);
            dst -= (size_t)0;                // dst indexed by idx below
            dst += 0;
            // store target: wqkv4[r*DD4 + idx] == dst[idx]
        }
        float4 v = reinterpret_cast<const float4*>(src)[idx];
        ushort4 u;
        u.x = f2bf(v.x * scale); u.y = f2bf(v.y * scale);
        u.z = f2bf(v.z * scale); u.w = f2bf(v.w * scale);
        dst[idx] = u;
    }
}

#define MFMA(a, b, c) __builtin_amdgcn_mfma_f32_16x16x32_bf16(a, b, c, 0, 0, 0)
#define SB() __builtin_amdgcn_sched_barrier(0)
#define BAR() __builtin_amdgcn_s_barrier()
#define LGKM0() asm volatile("s_waitcnt lgkmcnt(0)" ::: "memory")

// ======== 256x256 4-phase pipelined NT GEMM core (K=1024, lda=ldb=1024) ====
__device__ __forceinline__ void gemm256_core(
    const unsigned short* __restrict__ Ab,
    const unsigned short* __restrict__ Bb,
    int m0, int n0,
    unsigned short (&As)[2][256 * 64], unsigned short (&Bs)[2][256 * 64],
    f32x4 (&acc)[8][4])
{
    constexpr int LD = 1024, NK = 16;
    const int tid = threadIdx.x;
    const int l = tid & 63, w = tid >> 6;
    const int wr = w >> 2, wc = w & 3;

    const int srow = w * 8 + (l >> 3);
    const int scol = ((l & 7) ^ (l >> 3)) * 8;
    const size_t ldst = (size_t)w * 1024 + (size_t)l * 16;

    auto stageA = [&](int t, int h, int b) {
        const unsigned short* src = Ab + (size_t)(m0 + h * 128 + srow) * LD + t * 64 + scol;
        char* dst = (char*)&As[b][0] + h * 16384 + ldst;
        gload_lds16(src, dst);
        gload_lds16(src + (size_t)64 * LD, dst + 8192);
    };
    auto stageB = [&](int t, int h, int b) {
        const unsigned short* src = Bb + (size_t)(n0 + h * 128 + srow) * LD + t * 64 + scol;
        char* dst = (char*)&Bs[b][0] + h * 16384 + ldst;
        gload_lds16(src, dst);
        gload_lds16(src + (size_t)64 * LD, dst + 8192);
    };

    const int l15 = l & 15, l7 = l & 7;
    const int s0 = (((l >> 4) ^ l7) * 16);
    const int s1 = ((((l >> 4) + 4) ^ l7) * 16);

    bf16x8 Af[4][2], Bf0[2][2], Bf1[2][2];

    stageA(0, 0, 0); stageA(0, 1, 0); stageB(0, 0, 0); stageB(0, 1, 0);
    stageB(1, 0, 1); stageB(1, 1, 1);
    asm volatile("s_waitcnt vmcnt(4)" ::: "memory");
    SB(); BAR(); SB();

    for (int t = 0; t < NK; ++t) {
        const int b = t & 1, bn = b ^ 1;
        const char* ab = (const char*)&As[b][0] + (wr * 128 + l15) * 128;
        const char* bb = (const char*)&Bs[b][0] + (wc * 64 + l15) * 128;

        // P1: Q(0,0); stage A0(t+1)
        #pragma unroll
        for (int mi = 0; mi < 4; ++mi) {
            Af[mi][0] = *(const bf16x8*)(ab + mi * 2048 + s0);
            Af[mi][1] = *(const bf16x8*)(ab + mi * 2048 + s1);
        }
        #pragma unroll
        for (int ni = 0; ni < 2; ++ni) {
            Bf0[ni][0] = *(const bf16x8*)(bb + ni * 2048 + s0);
            Bf0[ni][1] = *(const bf16x8*)(bb + ni * 2048 + s1);
        }
        if (t + 1 < NK) stageA(t + 1, 0, bn);
        BAR(); LGKM0(); SB();
        __builtin_amdgcn_s_setprio(1);
        #pragma unroll
        for (int mi = 0; mi < 4; ++mi)
            #pragma unroll
            for (int ni = 0; ni < 2; ++ni) {
                acc[mi][ni] = MFMA(Af[mi][0], Bf0[ni][0], acc[mi][ni]);
                acc[mi][ni] = MFMA(Af[mi][1], Bf0[ni][1], acc[mi][ni]);
            }
        __builtin_amdgcn_s_setprio(0);
        SB(); BAR(); SB();

        // P2: Q(0,1); stage A1(t+1)
        #pragma unroll
        for (int ni = 0; ni < 2; ++ni) {
            Bf1[ni][0] = *(const bf16x8*)(bb + 4096 + ni * 2048 + s0);
            Bf1[ni][1] = *(const bf16x8*)(bb + 4096 + ni * 2048 + s1);
        }
        if (t + 1 < NK) stageA(t + 1, 1, bn);
        BAR(); LGKM0(); SB();
        __builtin_amdgcn_s_setprio(1);
        #pragma unroll
        for (int mi = 0; mi < 4; ++mi)
            #pragma unroll
            for (int ni = 0; ni < 2; ++ni) {
                acc[mi][2 + ni] = MFMA(Af[mi][0], Bf1[ni][0], acc[mi][2 + ni]);
                acc[mi][2 + ni] = MFMA(Af[mi][1], Bf1[ni][1], acc[mi][2 + ni]);
            }
        __builtin_amdgcn_s_setprio(0);
        SB(); BAR(); SB();

        // P3: Q(1,1); reads A qm1; stage B0(t+2) into b
        #pragma unroll
        for (int mi = 0; mi < 4; ++mi) {
            Af[mi][0] = *(const bf16x8*)(ab + 8192 + mi * 2048 + s0);
            Af[mi][1] = *(const bf16x8*)(ab + 8192 + mi * 2048 + s1);
        }
        if (t + 2 < NK) stageB(t + 2, 0, b);
        BAR(); LGKM0(); SB();
        __builtin_amdgcn_s_setprio(1);
        #pragma unroll
        for (int mi = 0; mi < 4; ++mi)
            #pragma unroll
            for (int ni = 0; ni < 2; ++ni) {
                acc[4 + mi][2 + ni] = MFMA(Af[mi][0], Bf1[ni][0], acc[4 + mi][2 + ni]);
                acc[4 + mi][2 + ni] = MFMA(Af[mi][1], Bf1[ni][1], acc[4 + mi][2 + ni]);
            }
        __builtin_amdgcn_s_setprio(0);
        SB(); BAR(); SB();

        // P4: Q(1,0); no reads; stage B1(t+2)
        if (t + 2 < NK) stageB(t + 2, 1, b);
        BAR(); SB();
        __builtin_amdgcn_s_setprio(1);
        #pragma unroll
        for (int mi = 0; mi < 4; ++mi)
            #pragma unroll
            for (int ni = 0; ni < 2; ++ni) {
                acc[4 + mi][ni] = MFMA(Af[mi][0], Bf0[ni][0], acc[4 + mi][ni]);
                acc[4 + mi][ni] = MFMA(Af[mi][1], Bf0[ni][1], acc[4 + mi][ni]);
            }
        __builtin_amdgcn_s_setprio(0);
        if (t + 2 < NK) {
            asm volatile("s_waitcnt vmcnt(4)" ::: "memory");
        } else if (t + 1 < NK) {
            asm volatile("s_waitcnt vmcnt(0)" ::: "memory");
        }
        SB(); BAR(); SB();
    }
}

// ======== d1: Q+K projection. 256 blocks (32 x 8), exact 1 round ======
__global__ __launch_bounds__(512, 2) void qk_proj(
    const unsigned short* __restrict__ xb, const unsigned short* __restrict__ wqkv,
    unsigned short* __restrict__ qb, unsigned short* __restrict__ kb)
{
    const int wg = xcd_remap(blockIdx.x, 256);
    const int mt = wg & 31, nt = wg >> 5;      // nt 0..7
    const int m0 = mt * 256, n0 = nt * 256;

    __shared__ unsigned short As[2][256 * 64];
    __shared__ unsigned short Bs[2][256 * 64];
    f32x4 acc[8][4] = {};

    gemm256_core(xb, wqkv, m0, n0, As, Bs, acc);

    const int tid = threadIdx.x;
    const int l = tid & 63, w = tid >> 6;
    const int wr = w >> 2, wc = w & 3;
    const int crow = (l >> 4) * 4, ccol = l & 15;
    unsigned short* C = (nt < 4) ? qb : kb;
    const int cb = (nt < 4) ? n0 : n0 - 1024;
    #pragma unroll
    for (int mi = 0; mi < 8; ++mi)
        #pragma unroll
        for (int ni = 0; ni < 4; ++ni) {
            const size_t rbase = (size_t)(m0 + wr * 128 + mi * 16 + crow);
            const size_t cg = (size_t)(cb + wc * 64 + ni * 16 + ccol);
            #pragma unroll
            for (int r = 0; r < 4; ++r)
                C[(rbase + r) * 1024 + cg] = f2bf(acc[mi][ni][r]);
        }
}

// ======== 128x128 BK=64 core, counted-vmcnt 2-deep pipeline ========
__device__ __forceinline__ void gemm128_core64(
    const unsigned short* __restrict__ Ab, int lda,
    const unsigned short* __restrict__ Bb, int ldb,
    int m0, int n0, int nk,
    unsigned short (&As)[2][128 * 64], unsigned short (&Bs)[2][128 * 64],
    f32x4 (&acc)[4][4])
{
    const int tid = threadIdx.x;
    const int l = tid & 63, w = tid >> 6;
    const int wr = w >> 1, wc = w & 1;
    const int l15 = l & 15;

    const int srow = w * 8 + (l >> 3);
    const int scol = ((l & 7) ^ (l >> 3)) * 8;     // pre-swizzled source col
    const size_t ldst = (size_t)w * 1024 + (size_t)l * 16;

    auto stage = [&](int t, int b) {
        const int k0 = t * 64;
        #pragma unroll
        for (int i = 0; i < 4; ++i) {
            gload_lds16(Ab + (size_t)(m0 + i * 32 + srow) * lda + k0 + scol,
                        (char*)&As[b][0] + i * 4096 + ldst);
            gload_lds16(Bb + (size_t)(n0 + i * 32 + srow) * ldb + k0 + scol,
                        (char*)&Bs[b][0] + i * 4096 + ldst);
        }
    };

    const int s0 = (((l >> 4) ^ (l & 7)) * 16);
    const int s1 = ((((l >> 4) + 4) ^ (l & 7)) * 16);

    stage(0, 0);
    if (nk > 1) {
        stage(1, 1);
        asm volatile("s_waitcnt vmcnt(8)" ::: "memory");
    } else {
        asm volatile("s_waitcnt vmcnt(0)" ::: "memory");
    }
    SB(); BAR(); SB();

    for (int t = 0; t < nk; ++t) {
        const int b = t & 1;
        const char* ab = (const char*)&As[b][0] + (wr * 64 + l15) * 128;
        const char* bb = (const char*)&Bs[b][0] + (wc * 64 + l15) * 128;
        bf16x8 af[4][2], bfr[4][2];
        #pragma unroll
        for (int m = 0; m < 4; ++m) {
            af[m][0] = *(const bf16x8*)(ab + m * 2048 + s0);
            af[m][1] = *(const bf16x8*)(ab + m * 2048 + s1);
        }
        #pragma unroll
        for (int n = 0; n < 4; ++n) {
            bfr[n][0] = *(const bf16x8*)(bb + n * 2048 + s0);
            bfr[n][1] = *(const bf16x8*)(bb + n * 2048 + s1);
        }
        LGKM0(); SB();
        BAR(); SB();
        if (t + 2 < nk) stage(t + 2, b);

        __builtin_amdgcn_s_setprio(1);
        #pragma unroll
        for (int m = 0; m < 4; ++m)
            #pragma unroll
            for (int n = 0; n < 4; ++n) {
                acc[m][n] = MFMA(af[m][0], bfr[n][0], acc[m][n]);
                acc[m][n] = MFMA(af[m][1], bfr[n][1], acc[m][n]);
            }
        __builtin_amdgcn_s_setprio(0);

        if (t + 2 < nk) {
            asm volatile("s_waitcnt vmcnt(8)" ::: "memory");
        } else if (t + 1 < nk) {
            asm volatile("s_waitcnt vmcnt(0)" ::: "memory");
        }
        SB(); BAR(); SB();
    }
}

// ======== d2: V-proj (512 blocks) + causal scores (544 blocks) @128² =======
__global__ __launch_bounds__(256) void v_scores128(
    const unsigned short* __restrict__ xb, const unsigned short* __restrict__ wv,
    const unsigned short* __restrict__ qb, const unsigned short* __restrict__ kb,
    unsigned short* __restrict__ vt, unsigned short* __restrict__ sc)
{
    const int wg = xcd_remap(blockIdx.x, 1056);

    __shared__ unsigned short As[2][128 * 64];
    __shared__ unsigned short Bs[2][128 * 64];
    f32x4 acc[4][4] = {};

    const int tid = threadIdx.x;
    const int l = tid & 63, w = tid >> 6;
    const int wr = w >> 1, wc = w & 1;
    const int crow = (l >> 4) * 4, ccol = l & 15;

    if (wg < 512) {
        const int mt = wg & 63, nt = wg >> 6;   // 64 x 8
        const int m0 = mt * 128, n0 = nt * 128;
        gemm128_core64(xb, 1024, wv, 1024, m0, n0, 16, As, Bs, acc);
        #pragma unroll
        for (int m = 0; m < 4; ++m)
            #pragma unroll
            for (int n = 0; n < 4; ++n) {
                const int rbase = m0 + wr * 64 + m * 16 + crow;
                const int o = n0 + wc * 64 + n * 16 + ccol;
                ushort4 u;
                u.x = f2bf(acc[m][n][0]);
                u.y = f2bf(acc[m][n][1]);
                u.z = f2bf(acc[m][n][2]);
                u.w = f2bf(acc[m][n][3]);
                *reinterpret_cast<ushort4*>(&vt[(size_t)o * 8192 + rbase]) = u;
            }
    } else {
        const int s = wg - 512;
        const int z = s / 136, r = s % 136;
        int mt = (int)((__builtin_sqrtf(8.f * r + 1.f) - 1.f) * 0.5f);
        while ((mt + 1) * (mt + 2) / 2 <= r) ++mt;
        while (mt * (mt + 1) / 2 > r) --mt;
        const int nt = r - mt * (mt + 1) / 2;
        const int m0 = mt * 128, n0 = nt * 128;
        const unsigned short* Ab = qb + (size_t)z * 2048 * 1024;
        const unsigned short* Bb = kb + (size_t)z * 2048 * 1024;
        gemm128_core64(Ab, 1024, Bb, 1024, m0, n0, 16, As, Bs, acc);
        unsigned short* C = sc + (size_t)z * 2048 * 2048;
        #pragma unroll
        for (int m = 0; m < 4; ++m)
            #pragma unroll
            for (int n = 0; n < 4; ++n) {
                const size_t rbase = (size_t)(m0 + wr * 64 + m * 16 + crow);
                const size_t cg = (size_t)(n0 + wc * 64 + n * 16 + ccol);
                #pragma unroll
                for (int r2 = 0; r2 < 4; ++r2)
                    C[(rbase + r2) * 2048 + cg] = f2bf(acc[m][n][r2]);
            }
    }
}

// ======== PV GEMM: 128x128 BK=64 core, fp32 out, causal K-limit ========
// Flat 512-block grid, heavy-light paired: ids c and c+256 decode to mt=j and
// mt=15-j, so if HW assigns ids round-robin the two blocks sharing a CU have
// constant combined work (makespan = avg-bound, not max-bound).
__global__ __launch_bounds__(256) void gemm128_pv(
    const unsigned short* __restrict__ A, int lda, long long sA,
    const unsigned short* __restrict__ B, int ldb, long long sB,
    float* __restrict__ C, int ldc, long long sC, int K)
{
    const int orig = blockIdx.x;
    const int h = orig >> 8;                   // 0/1 half
    const int c = xcd_remap(orig & 255, 256);
    const int z = c >> 6;
    const int rem = c & 63;
    const int nt = rem >> 3;
    const int j = rem & 7;
    const int mt = h ? (15 - j) : j;

    const unsigned short* Ab = A + (size_t)z * sA;
    const unsigned short* Bb = B + (size_t)z * sB;
    const int Keff = ((mt + 1) * 128 < K) ? (mt + 1) * 128 : K;
    const int nk = Keff >> 6;

    __shared__ unsigned short As[2][128 * 64];
    __shared__ unsigned short Bs[2][128 * 64];
    f32x4 acc[4][4] = {};

    gemm128_core64(Ab, lda, Bb, ldb, mt * 128, nt * 128, nk, As, Bs, acc);

    const int tid = threadIdx.x;
    const int l = tid & 63, w = tid >> 6;
    const int wr = w >> 1, wc = w & 1;
    const int crow = (l >> 4) * 4, ccol = l & 15;
    float* Cb = C + (size_t)z * sC;
    #pragma unroll
    for (int m = 0; m < 4; ++m)
        #pragma unroll
        for (int n = 0; n < 4; ++n) {
            const size_t rbase = (size_t)(mt * 128 + wr * 64 + m * 16 + crow);
            const size_t cg = (size_t)(nt * 128 + wc * 64 + n * 16 + ccol);
            #pragma unroll
            for (int r = 0; r < 4; ++r)
                Cb[(rbase + r) * ldc + cg] = acc[m][n][r];
        }
}

// ---------------- causal row softmax: wave-per-row, no LDS, no barriers -----
// grid 2048 x 256 threads: wave w of block b handles row b*4+w.
// Passes of 512 cols (64 lanes x 8). Reads cols <= q; writes cols < wlim.
__global__ __launch_bounds__(256) void softmax_causal(unsigned short* __restrict__ P) {
    const int S = 2048;
    const int w = threadIdx.x >> 6, l = threadIdx.x & 63;
    const int gq = blockIdx.x * 4 + w;
    const int q = gq & (S - 1);
    unsigned short* row = P + (size_t)gq * S;
    const int wlim = ((q >> 7) + 1) << 7;
    const float NEG = -__builtin_huge_valf();

    float f[4][8];
    #pragma unroll
    for (int p = 0; p < 4; ++p) {
        const int c0 = p * 512 + l * 8;
        if (p * 512 <= q && c0 <= q) {
            uint4 rv = *reinterpret_cast<const uint4*>(row + c0);
            unsigned short us[8];
            us[0] = rv.x & 0xffff; us[1] = rv.x >> 16;
            us[2] = rv.y & 0xffff; us[3] = rv.y >> 16;
            us[4] = rv.z & 0xffff; us[5] = rv.z >> 16;
            us[6] = rv.w & 0xffff; us[7] = rv.w >> 16;
            #pragma unroll
            for (int i = 0; i < 8; ++i)
                f[p][i] = (c0 + i <= q) ? bf2f(us[i]) : NEG;
        } else {
            #pragma unroll
            for (int i = 0; i < 8; ++i) f[p][i] = NEG;
        }
    }

    float m = NEG;
    #pragma unroll
    for (int p = 0; p < 4; ++p)
        #pragma unroll
        for (int i = 0; i < 8; ++i) m = fmaxf(m, f[p][i]);
    #pragma unroll
    for (int o = 1; o < 64; o <<= 1) m = fmaxf(m, __shfl_xor(m, o));

    float s = 0.f;
    #pragma unroll
    for (int p = 0; p < 4; ++p)
        #pragma unroll
        for (int i = 0; i < 8; ++i) {
            f[p][i] = exp2f((f[p][i] - m) * 1.44269504f);   // -inf -> 0
            s += f[p][i];
        }
    #pragma unroll
    for (int o = 1; o < 64; o <<= 1) s += __shfl_xor(s, o);
    const float inv = 1.0f / s;

    #pragma unroll
    for (int p = 0; p < 4; ++p) {
        const int c0 = p * 512 + l * 8;
        if (p * 512 < wlim && c0 < wlim) {
            uint4 ov;
            ov.x = f2bf(f[p][0] * inv) | ((unsigned int)f2bf(f[p][1] * inv) << 16);
            ov.y = f2bf(f[p][2] * inv) | ((unsigned int)f2bf(f[p][3] * inv) << 16);
            ov.z = f2bf(f[p][4] * inv) | ((unsigned int)f2bf(f[p][5] * inv) << 16);
            ov.w = f2bf(f[p][6] * inv) | ((unsigned int)f2bf(f[p][7] * inv) << 16);
            *reinterpret_cast<uint4*>(row + c0) = ov;
        }
    }
}

extern "C" void kernel_launch(void* const* d_in, const int* in_sizes, int n_in,
                              void* d_out, int out_size, void* d_ws, size_t ws_size,
                              hipStream_t stream) {
    const float* x  = (const float*)d_in[0];
    const float* Wq = (const float*)d_in[1];
    const float* Wk = (const float*)d_in[2];
    const float* Wv = (const float*)d_in[3];
    float* out = (float*)d_out;

    const int Bz = 4, S = 2048, D = 1024;
    const int MS = Bz * S;       // 8192
    const int DD = D * D;

    char* ws = (char*)d_ws;
    unsigned short* xb   = (unsigned short*)(ws);                      // 16 MB [8192][1024]
    unsigned short* wqkv = (unsigned short*)(ws + (16ull << 20));      //  6 MB [3072][1024]
    unsigned short* qb   = (unsigned short*)(ws + (22ull << 20));      // 16 MB [8192][1024]
    unsigned short* kb   = (unsigned short*)(ws + (38ull << 20));      // 16 MB [8192][1024]
    unsigned short* vt   = (unsigned short*)(ws + (54ull << 20));      // 16 MB [1024][8192] (V^T)
    unsigned short* sc   = (unsigned short*)(ws + (70ull << 20));      // 32 MB [4][2048][2048]

    // 1. bf16 conversion, single dispatch (softmax scale folded into Wq)
    cvt_all<<<2048, 256, 0, stream>>>(x, Wq, Wk, Wv, xb, wqkv);

    // 2. d1: Q,K projection (256 blocks @256², exact machine fill)
    qk_proj<<<256, 512, 0, stream>>>(xb, wqkv, qb, kb);

    // 3. d2: V projection (512) + causal scores (544) @128²/BK=64, 2-deep vmcnt
    v_scores128<<<1056, 256, 0, stream>>>(xb, wqkv + (size_t)2 * DD, qb, kb, vt, sc);

    // 4. causal softmax in place (wave-per-row)
    softmax_causal<<<2048, 256, 0, stream>>>(sc);

    // 5. out = P * V == P * Vt^T  (128²/BK=64 core, causal K-limit, paired)
    gemm128_pv<<<512, 256, 0, stream>>>(
        sc, S, (long long)S * S, vt, MS, S, out, D, (long long)S * D, S);
}

// Round 12
// 144.816 us; speedup vs baseline: 1.1045x; 1.0829x over previous
//
#include <hip/hip_runtime.h>
#include <hip/hip_bf16.h>
#include <stdint.h>

typedef __attribute__((ext_vector_type(8))) short bf16x8;
typedef __attribute__((ext_vector_type(4))) float f32x4;

__device__ __forceinline__ float bf2f(unsigned short u) {
    union { unsigned int i; float f; } z; z.i = ((unsigned int)u) << 16; return z.f;
}
__device__ __forceinline__ unsigned short f2bf(float f) {
    union { float f; unsigned int i; } z; z.f = f;
    unsigned int x = z.i;
    unsigned int r = x + 0x7fffu + ((x >> 16) & 1u);
    return (unsigned short)(r >> 16);
}

typedef const __attribute__((address_space(1))) unsigned int* gp_t;
typedef __attribute__((address_space(3))) unsigned int* lp_t;

__device__ __forceinline__ void gload_lds16(const void* g, void* l) {
    __builtin_amdgcn_global_load_lds((gp_t)g, (lp_t)l, 16, 0, 0);
}

// bijective XCD-aware remap (m204 form) on a linear block id
__device__ __forceinline__ int xcd_remap(int orig, int nwg) {
    const int q = nwg >> 3, r = nwg & 7;
    const int xcd = orig & 7, pos = orig >> 3;
    return (xcd < r ? xcd * (q + 1) : r * (q + 1) + (xcd - r) * q) + pos;
}

// ---------------- fp32 -> bf16 conversion: x and Wv ----------------
__global__ __launch_bounds__(256) void cvt_xv(const float* __restrict__ x,
                                              const float* __restrict__ wv,
                                              unsigned short* __restrict__ xb,
                                              unsigned short* __restrict__ wvb) {
    const int NX = 1 << 21;          // 8192*1024/4
    const int DD4 = 1 << 18;         // 1024*1024/4
    const int total = NX + DD4;
    int i = blockIdx.x * 256 + threadIdx.x;
    const int stride = gridDim.x * 256;
    for (; i < total; i += stride) {
        float4 v = (i < NX) ? reinterpret_cast<const float4*>(x)[i]
                            : reinterpret_cast<const float4*>(wv)[i - NX];
        ushort4 u;
        u.x = f2bf(v.x); u.y = f2bf(v.y); u.z = f2bf(v.z); u.w = f2bf(v.w);
        if (i < NX) reinterpret_cast<ushort4*>(xb)[i] = u;
        else        reinterpret_cast<ushort4*>(wvb)[i - NX] = u;
    }
}

// ---------------- transpose Wq (x 1/32) and Wk into bf16 wqT, wkT ----------
// wqT[d][o] = Wq[o][d] * 1/32 ; wkT[d][o] = Wk[o][d].  64x64 LDS tiles.
__global__ __launch_bounds__(256) void tr_w(const float* __restrict__ wq,
                                            const float* __restrict__ wk,
                                            unsigned short* __restrict__ wqT,
                                            unsigned short* __restrict__ wkT) {
    const int id = blockIdx.x;           // 512 = 2 * 256 tiles
    const int m = id >> 8;               // 0: Wq, 1: Wk
    const int t = id & 255;
    const int tr = t >> 4, tc = t & 15;  // tile coords (row, col) in src
    const float* src = m ? wk : wq;
    unsigned short* dst = m ? wkT : wqT;
    const float scale = m ? 1.0f : 0.03125f;

    __shared__ unsigned short tile[64][65];   // [src col][src row]
    const int tid = threadIdx.x;
    const int r0 = tid >> 4;             // 0..15
    const int c4 = tid & 15;             // float4 index within 64 cols
    #pragma unroll
    for (int p = 0; p < 4; ++p) {
        const int r = p * 16 + r0;
        float4 v = reinterpret_cast<const float4*>(
            src + (size_t)(tr * 64 + r) * 1024 + tc * 64)[c4];
        tile[c4 * 4 + 0][r] = f2bf(v.x * scale);
        tile[c4 * 4 + 1][r] = f2bf(v.y * scale);
        tile[c4 * 4 + 2][r] = f2bf(v.z * scale);
        tile[c4 * 4 + 3][r] = f2bf(v.w * scale);
    }
    __syncthreads();
    const int cr = tid >> 2;             // out-row within tile (src col), 0..63
    const int q4 = tid & 3;
    #pragma unroll
    for (int p = 0; p < 4; ++p) {
        const int off = (q4 * 4 + p) * 4;   // short offset 0..60
        ushort4 u;
        u.x = tile[cr][off + 0]; u.y = tile[cr][off + 1];
        u.z = tile[cr][off + 2]; u.w = tile[cr][off + 3];
        *reinterpret_cast<ushort4*>(dst + (size_t)(tc * 64 + cr) * 1024 + tr * 64 + off) = u;
    }
}

#define MFMA(a, b, c) __builtin_amdgcn_mfma_f32_16x16x32_bf16(a, b, c, 0, 0, 0)
#define SB() __builtin_amdgcn_sched_barrier(0)
#define BAR() __builtin_amdgcn_s_barrier()
#define LGKM0() asm volatile("s_waitcnt lgkmcnt(0)" ::: "memory")

// ======== 256x256 4-phase pipelined NT GEMM core (K=1024, lda=ldb=1024) ====
__device__ __forceinline__ void gemm256_core(
    const unsigned short* __restrict__ Ab,
    const unsigned short* __restrict__ Bb,
    int m0, int n0,
    unsigned short (&As)[2][256 * 64], unsigned short (&Bs)[2][256 * 64],
    f32x4 (&acc)[8][4])
{
    constexpr int LD = 1024, NK = 16;
    const int tid = threadIdx.x;
    const int l = tid & 63, w = tid >> 6;
    const int wr = w >> 2, wc = w & 3;

    const int srow = w * 8 + (l >> 3);
    const int scol = ((l & 7) ^ (l >> 3)) * 8;
    const size_t ldst = (size_t)w * 1024 + (size_t)l * 16;

    auto stageA = [&](int t, int h, int b) {
        const unsigned short* src = Ab + (size_t)(m0 + h * 128 + srow) * LD + t * 64 + scol;
        char* dst = (char*)&As[b][0] + h * 16384 + ldst;
        gload_lds16(src, dst);
        gload_lds16(src + (size_t)64 * LD, dst + 8192);
    };
    auto stageB = [&](int t, int h, int b) {
        const unsigned short* src = Bb + (size_t)(n0 + h * 128 + srow) * LD + t * 64 + scol;
        char* dst = (char*)&Bs[b][0] + h * 16384 + ldst;
        gload_lds16(src, dst);
        gload_lds16(src + (size_t)64 * LD, dst + 8192);
    };

    const int l15 = l & 15, l7 = l & 7;
    const int s0 = (((l >> 4) ^ l7) * 16);
    const int s1 = ((((l >> 4) + 4) ^ l7) * 16);

    bf16x8 Af[4][2], Bf0[2][2], Bf1[2][2];

    stageA(0, 0, 0); stageA(0, 1, 0); stageB(0, 0, 0); stageB(0, 1, 0);
    stageB(1, 0, 1); stageB(1, 1, 1);
    asm volatile("s_waitcnt vmcnt(4)" ::: "memory");
    SB(); BAR(); SB();

    for (int t = 0; t < NK; ++t) {
        const int b = t & 1, bn = b ^ 1;
        const char* ab = (const char*)&As[b][0] + (wr * 128 + l15) * 128;
        const char* bb = (const char*)&Bs[b][0] + (wc * 64 + l15) * 128;

        // P1: Q(0,0); stage A0(t+1)
        #pragma unroll
        for (int mi = 0; mi < 4; ++mi) {
            Af[mi][0] = *(const bf16x8*)(ab + mi * 2048 + s0);
            Af[mi][1] = *(const bf16x8*)(ab + mi * 2048 + s1);
        }
        #pragma unroll
        for (int ni = 0; ni < 2; ++ni) {
            Bf0[ni][0] = *(const bf16x8*)(bb + ni * 2048 + s0);
            Bf0[ni][1] = *(const bf16x8*)(bb + ni * 2048 + s1);
        }
        if (t + 1 < NK) stageA(t + 1, 0, bn);
        BAR(); LGKM0(); SB();
        __builtin_amdgcn_s_setprio(1);
        #pragma unroll
        for (int mi = 0; mi < 4; ++mi)
            #pragma unroll
            for (int ni = 0; ni < 2; ++ni) {
                acc[mi][ni] = MFMA(Af[mi][0], Bf0[ni][0], acc[mi][ni]);
                acc[mi][ni] = MFMA(Af[mi][1], Bf0[ni][1], acc[mi][ni]);
            }
        __builtin_amdgcn_s_setprio(0);
        SB(); BAR(); SB();

        // P2: Q(0,1); stage A1(t+1)
        #pragma unroll
        for (int ni = 0; ni < 2; ++ni) {
            Bf1[ni][0] = *(const bf16x8*)(bb + 4096 + ni * 2048 + s0);
            Bf1[ni][1] = *(const bf16x8*)(bb + 4096 + ni * 2048 + s1);
        }
        if (t + 1 < NK) stageA(t + 1, 1, bn);
        BAR(); LGKM0(); SB();
        __builtin_amdgcn_s_setprio(1);
        #pragma unroll
        for (int mi = 0; mi < 4; ++mi)
            #pragma unroll
            for (int ni = 0; ni < 2; ++ni) {
                acc[mi][2 + ni] = MFMA(Af[mi][0], Bf1[ni][0], acc[mi][2 + ni]);
                acc[mi][2 + ni] = MFMA(Af[mi][1], Bf1[ni][1], acc[mi][2 + ni]);
            }
        __builtin_amdgcn_s_setprio(0);
        SB(); BAR(); SB();

        // P3: Q(1,1); reads A qm1; stage B0(t+2) into b
        #pragma unroll
        for (int mi = 0; mi < 4; ++mi) {
            Af[mi][0] = *(const bf16x8*)(ab + 8192 + mi * 2048 + s0);
            Af[mi][1] = *(const bf16x8*)(ab + 8192 + mi * 2048 + s1);
        }
        if (t + 2 < NK) stageB(t + 2, 0, b);
        BAR(); LGKM0(); SB();
        __builtin_amdgcn_s_setprio(1);
        #pragma unroll
        for (int mi = 0; mi < 4; ++mi)
            #pragma unroll
            for (int ni = 0; ni < 2; ++ni) {
                acc[4 + mi][2 + ni] = MFMA(Af[mi][0], Bf1[ni][0], acc[4 + mi][2 + ni]);
                acc[4 + mi][2 + ni] = MFMA(Af[mi][1], Bf1[ni][1], acc[4 + mi][2 + ni]);
            }
        __builtin_amdgcn_s_setprio(0);
        SB(); BAR(); SB();

        // P4: Q(1,0); no reads; stage B1(t+2)
        if (t + 2 < NK) stageB(t + 2, 1, b);
        BAR(); SB();
        __builtin_amdgcn_s_setprio(1);
        #pragma unroll
        for (int mi = 0; mi < 4; ++mi)
            #pragma unroll
            for (int ni = 0; ni < 2; ++ni) {
                acc[4 + mi][ni] = MFMA(Af[mi][0], Bf0[ni][0], acc[4 + mi][ni]);
                acc[4 + mi][ni] = MFMA(Af[mi][1], Bf0[ni][1], acc[4 + mi][ni]);
            }
        __builtin_amdgcn_s_setprio(0);
        if (t + 2 < NK) {
            asm volatile("s_waitcnt vmcnt(4)" ::: "memory");
        } else if (t + 1 < NK) {
            asm volatile("s_waitcnt vmcnt(0)" ::: "memory");
        }
        SB(); BAR(); SB();
    }
}

// ======== d1: T-proj (128 blocks) + V-proj (128 blocks) @256², 1 round =====
// T = x * Wst^T (normal bf16 store); V = x * Wv^T stored transposed into vt.
__global__ __launch_bounds__(512, 2) void tv_proj(
    const unsigned short* __restrict__ xb, const unsigned short* __restrict__ wst,
    const unsigned short* __restrict__ wvb,
    unsigned short* __restrict__ tb, unsigned short* __restrict__ vt)
{
    const int wg = xcd_remap(blockIdx.x, 256);

    __shared__ unsigned short As[2][256 * 64];
    __shared__ unsigned short Bs[2][256 * 64];
    f32x4 acc[8][4] = {};

    const int tid = threadIdx.x;
    const int l = tid & 63, w = tid >> 6;
    const int wr = w >> 2, wc = w & 3;
    const int crow = (l >> 4) * 4, ccol = l & 15;

    if (wg < 128) {
        // T-projection: tb[s][j] = sum_d xb[s][d] * wst[j][d]
        const int mt = wg & 31, nt = wg >> 5;      // nt 0..3
        const int m0 = mt * 256, n0 = nt * 256;
        gemm256_core(xb, wst, m0, n0, As, Bs, acc);
        #pragma unroll
        for (int mi = 0; mi < 8; ++mi)
            #pragma unroll
            for (int ni = 0; ni < 4; ++ni) {
                const size_t rbase = (size_t)(m0 + wr * 128 + mi * 16 + crow);
                const size_t cg = (size_t)(n0 + wc * 64 + ni * 16 + ccol);
                #pragma unroll
                for (int r = 0; r < 4; ++r)
                    tb[(rbase + r) * 1024 + cg] = f2bf(acc[mi][ni][r]);
            }
    } else {
        // V-projection, stored transposed into vt[1024][8192]
        const int v = wg - 128;
        const int mt = v & 31, nt = v >> 5;        // nt 0..3
        const int m0 = mt * 256, n0 = nt * 256;
        gemm256_core(xb, wvb, m0, n0, As, Bs, acc);
        #pragma unroll
        for (int mi = 0; mi < 8; ++mi)
            #pragma unroll
            for (int ni = 0; ni < 4; ++ni) {
                const int rbase = m0 + wr * 128 + mi * 16 + crow;
                const int o = n0 + wc * 64 + ni * 16 + ccol;
                ushort4 u;
                u.x = f2bf(acc[mi][ni][0]);
                u.y = f2bf(acc[mi][ni][1]);
                u.z = f2bf(acc[mi][ni][2]);
                u.w = f2bf(acc[mi][ni][3]);
                *reinterpret_cast<ushort4*>(&vt[(size_t)o * 8192 + rbase]) = u;
            }
    }
}

// ======== 128x128 BK=64 core, counted-vmcnt 2-deep pipeline ========
__device__ __forceinline__ void gemm128_core64(
    const unsigned short* __restrict__ Ab, int lda,
    const unsigned short* __restrict__ Bb, int ldb,
    int m0, int n0, int nk,
    unsigned short (&As)[2][128 * 64], unsigned short (&Bs)[2][128 * 64],
    f32x4 (&acc)[4][4])
{
    const int tid = threadIdx.x;
    const int l = tid & 63, w = tid >> 6;
    const int wr = w >> 1, wc = w & 1;
    const int l15 = l & 15;

    const int srow = w * 8 + (l >> 3);
    const int scol = ((l & 7) ^ (l >> 3)) * 8;     // pre-swizzled source col
    const size_t ldst = (size_t)w * 1024 + (size_t)l * 16;

    auto stage = [&](int t, int b) {
        const int k0 = t * 64;
        #pragma unroll
        for (int i = 0; i < 4; ++i) {
            gload_lds16(Ab + (size_t)(m0 + i * 32 + srow) * lda + k0 + scol,
                        (char*)&As[b][0] + i * 4096 + ldst);
            gload_lds16(Bb + (size_t)(n0 + i * 32 + srow) * ldb + k0 + scol,
                        (char*)&Bs[b][0] + i * 4096 + ldst);
        }
    };

    const int s0 = (((l >> 4) ^ (l & 7)) * 16);
    const int s1 = ((((l >> 4) + 4) ^ (l & 7)) * 16);

    stage(0, 0);
    if (nk > 1) {
        stage(1, 1);
        asm volatile("s_waitcnt vmcnt(8)" ::: "memory");
    } else {
        asm volatile("s_waitcnt vmcnt(0)" ::: "memory");
    }
    SB(); BAR(); SB();

    for (int t = 0; t < nk; ++t) {
        const int b = t & 1;
        const char* ab = (const char*)&As[b][0] + (wr * 64 + l15) * 128;
        const char* bb = (const char*)&Bs[b][0] + (wc * 64 + l15) * 128;
        bf16x8 af[4][2], bfr[4][2];
        #pragma unroll
        for (int m = 0; m < 4; ++m) {
            af[m][0] = *(const bf16x8*)(ab + m * 2048 + s0);
            af[m][1] = *(const bf16x8*)(ab + m * 2048 + s1);
        }
        #pragma unroll
        for (int n = 0; n < 4; ++n) {
            bfr[n][0] = *(const bf16x8*)(bb + n * 2048 + s0);
            bfr[n][1] = *(const bf16x8*)(bb + n * 2048 + s1);
        }
        LGKM0(); SB();
        BAR(); SB();
        if (t + 2 < nk) stage(t + 2, b);

        __builtin_amdgcn_s_setprio(1);
        #pragma unroll
        for (int m = 0; m < 4; ++m)
            #pragma unroll
            for (int n = 0; n < 4; ++n) {
                acc[m][n] = MFMA(af[m][0], bfr[n][0], acc[m][n]);
                acc[m][n] = MFMA(af[m][1], bfr[n][1], acc[m][n]);
            }
        __builtin_amdgcn_s_setprio(0);

        if (t + 2 < nk) {
            asm volatile("s_waitcnt vmcnt(8)" ::: "memory");
        } else if (t + 1 < nk) {
            asm volatile("s_waitcnt vmcnt(0)" ::: "memory");
        }
        SB(); BAR(); SB();
    }
}

// ======== d0: Wst[d'][d] = sum_o Wk[o][d'] * Wq_scaled[o][d]  (64 blocks) ===
__global__ __launch_bounds__(256) void wst128(
    const unsigned short* __restrict__ wkT, const unsigned short* __restrict__ wqT,
    unsigned short* __restrict__ wst)
{
    const int wg = xcd_remap(blockIdx.x, 64);
    const int mt = wg & 7, nt = wg >> 3;
    const int m0 = mt * 128, n0 = nt * 128;

    __shared__ unsigned short As[2][128 * 64];
    __shared__ unsigned short Bs[2][128 * 64];
    f32x4 acc[4][4] = {};

    gemm128_core64(wkT, 1024, wqT, 1024, m0, n0, 16, As, Bs, acc);

    const int tid = threadIdx.x;
    const int l = tid & 63, w = tid >> 6;
    const int wr = w >> 1, wc = w & 1;
    const int crow = (l >> 4) * 4, ccol = l & 15;
    #pragma unroll
    for (int m = 0; m < 4; ++m)
        #pragma unroll
        for (int n = 0; n < 4; ++n) {
            const size_t rbase = (size_t)(m0 + wr * 64 + m * 16 + crow);
            const size_t cg = (size_t)(n0 + wc * 64 + n * 16 + ccol);
            #pragma unroll
            for (int r = 0; r < 4; ++r)
                wst[(rbase + r) * 1024 + cg] = f2bf(acc[m][n][r]);
        }
}

// ======== d2: causal scores S = T * x^T (544 blocks @128²) ========
__global__ __launch_bounds__(256) void scores128(
    const unsigned short* __restrict__ tb, const unsigned short* __restrict__ xb,
    unsigned short* __restrict__ sc)
{
    const int wg = xcd_remap(blockIdx.x, 544);

    __shared__ unsigned short As[2][128 * 64];
    __shared__ unsigned short Bs[2][128 * 64];
    f32x4 acc[4][4] = {};

    const int z = wg / 136, r = wg % 136;
    int mt = (int)((__builtin_sqrtf(8.f * r + 1.f) - 1.f) * 0.5f);
    while ((mt + 1) * (mt + 2) / 2 <= r) ++mt;
    while (mt * (mt + 1) / 2 > r) --mt;
    const int nt = r - mt * (mt + 1) / 2;
    const int m0 = mt * 128, n0 = nt * 128;
    const unsigned short* Ab = tb + (size_t)z * 2048 * 1024;
    const unsigned short* Bb = xb + (size_t)z * 2048 * 1024;
    gemm128_core64(Ab, 1024, Bb, 1024, m0, n0, 16, As, Bs, acc);

    const int tid = threadIdx.x;
    const int l = tid & 63, w = tid >> 6;
    const int wr = w >> 1, wc = w & 1;
    const int crow = (l >> 4) * 4, ccol = l & 15;
    unsigned short* C = sc + (size_t)z * 2048 * 2048;
    #pragma unroll
    for (int m = 0; m < 4; ++m)
        #pragma unroll
        for (int n = 0; n < 4; ++n) {
            const size_t rbase = (size_t)(m0 + wr * 64 + m * 16 + crow);
            const size_t cg = (size_t)(n0 + wc * 64 + n * 16 + ccol);
            #pragma unroll
            for (int r2 = 0; r2 < 4; ++r2)
                C[(rbase + r2) * 2048 + cg] = f2bf(acc[m][n][r2]);
        }
}

// ======== PV GEMM: 128x128 BK=64 core, fp32 out, causal K-limit ========
__global__ __launch_bounds__(256) void gemm128_pv(
    const unsigned short* __restrict__ A, int lda, long long sA,
    const unsigned short* __restrict__ B, int ldb, long long sB,
    float* __restrict__ C, int ldc, long long sC, int K)
{
    const int orig = blockIdx.x;
    const int h = orig >> 8;                   // 0/1 half
    const int c = xcd_remap(orig & 255, 256);
    const int z = c >> 6;
    const int rem = c & 63;
    const int nt = rem >> 3;
    const int j = rem & 7;
    const int mt = h ? (15 - j) : j;

    const unsigned short* Ab = A + (size_t)z * sA;
    const unsigned short* Bb = B + (size_t)z * sB;
    const int Keff = ((mt + 1) * 128 < K) ? (mt + 1) * 128 : K;
    const int nk = Keff >> 6;

    __shared__ unsigned short As[2][128 * 64];
    __shared__ unsigned short Bs[2][128 * 64];
    f32x4 acc[4][4] = {};

    gemm128_core64(Ab, lda, Bb, ldb, mt * 128, nt * 128, nk, As, Bs, acc);

    const int tid = threadIdx.x;
    const int l = tid & 63, w = tid >> 6;
    const int wr = w >> 1, wc = w & 1;
    const int crow = (l >> 4) * 4, ccol = l & 15;
    float* Cb = C + (size_t)z * sC;
    #pragma unroll
    for (int m = 0; m < 4; ++m)
        #pragma unroll
        for (int n = 0; n < 4; ++n) {
            const size_t rbase = (size_t)(mt * 128 + wr * 64 + m * 16 + crow);
            const size_t cg = (size_t)(nt * 128 + wc * 64 + n * 16 + ccol);
            #pragma unroll
            for (int r = 0; r < 4; ++r)
                Cb[(rbase + r) * ldc + cg] = acc[m][n][r];
        }
}

// ---------------- causal row softmax: wave-per-row, no LDS, no barriers -----
__global__ __launch_bounds__(256) void softmax_causal(unsigned short* __restrict__ P) {
    const int S = 2048;
    const int w = threadIdx.x >> 6, l = threadIdx.x & 63;
    const int gq = blockIdx.x * 4 + w;
    const int q = gq & (S - 1);
    unsigned short* row = P + (size_t)gq * S;
    const int wlim = ((q >> 7) + 1) << 7;
    const float NEG = -__builtin_huge_valf();

    float f[4][8];
    #pragma unroll
    for (int p = 0; p < 4; ++p) {
        const int c0 = p * 512 + l * 8;
        if (p * 512 <= q && c0 <= q) {
            uint4 rv = *reinterpret_cast<const uint4*>(row + c0);
            unsigned short us[8];
            us[0] = rv.x & 0xffff; us[1] = rv.x >> 16;
            us[2] = rv.y & 0xffff; us[3] = rv.y >> 16;
            us[4] = rv.z & 0xffff; us[5] = rv.z >> 16;
            us[6] = rv.w & 0xffff; us[7] = rv.w >> 16;
            #pragma unroll
            for (int i = 0; i < 8; ++i)
                f[p][i] = (c0 + i <= q) ? bf2f(us[i]) : NEG;
        } else {
            #pragma unroll
            for (int i = 0; i < 8; ++i) f[p][i] = NEG;
        }
    }

    float m = NEG;
    #pragma unroll
    for (int p = 0; p < 4; ++p)
        #pragma unroll
        for (int i = 0; i < 8; ++i) m = fmaxf(m, f[p][i]);
    #pragma unroll
    for (int o = 1; o < 64; o <<= 1) m = fmaxf(m, __shfl_xor(m, o));

    float s = 0.f;
    #pragma unroll
    for (int p = 0; p < 4; ++p)
        #pragma unroll
        for (int i = 0; i < 8; ++i) {
            f[p][i] = exp2f((f[p][i] - m) * 1.44269504f);   // -inf -> 0
            s += f[p][i];
        }
    #pragma unroll
    for (int o = 1; o < 64; o <<= 1) s += __shfl_xor(s, o);
    const float inv = 1.0f / s;

    #pragma unroll
    for (int p = 0; p < 4; ++p) {
        const int c0 = p * 512 + l * 8;
        if (p * 512 < wlim && c0 < wlim) {
            uint4 ov;
            ov.x = f2bf(f[p][0] * inv) | ((unsigned int)f2bf(f[p][1] * inv) << 16);
            ov.y = f2bf(f[p][2] * inv) | ((unsigned int)f2bf(f[p][3] * inv) << 16);
            ov.z = f2bf(f[p][4] * inv) | ((unsigned int)f2bf(f[p][5] * inv) << 16);
            ov.w = f2bf(f[p][6] * inv) | ((unsigned int)f2bf(f[p][7] * inv) << 16);
            *reinterpret_cast<uint4*>(row + c0) = ov;
        }
    }
}

extern "C" void kernel_launch(void* const* d_in, const int* in_sizes, int n_in,
                              void* d_out, int out_size, void* d_ws, size_t ws_size,
                              hipStream_t stream) {
    const float* x  = (const float*)d_in[0];
    const float* Wq = (const float*)d_in[1];
    const float* Wk = (const float*)d_in[2];
    const float* Wv = (const float*)d_in[3];
    float* out = (float*)d_out;

    const int S = 2048;

    char* ws = (char*)d_ws;
    unsigned short* xb  = (unsigned short*)(ws);                  // 16 MB [8192][1024]
    unsigned short* wvb = (unsigned short*)(ws + (16ull << 20));  //  2 MB
    unsigned short* wqT = (unsigned short*)(ws + (18ull << 20));  //  2 MB (Wq^T * 1/32)
    unsigned short* wkT = (unsigned short*)(ws + (20ull << 20));  //  2 MB (Wk^T)
    unsigned short* wst = (unsigned short*)(ws + (22ull << 20));  //  2 MB Wst[d'][d]
    unsigned short* tb  = (unsigned short*)(ws + (24ull << 20));  // 16 MB T=[8192][1024]
    unsigned short* vt  = (unsigned short*)(ws + (40ull << 20));  // 16 MB V^T [1024][8192]
    unsigned short* sc  = (unsigned short*)(ws + (56ull << 20));  // 32 MB [4][2048][2048]

    // 1. conversions: x,Wv -> bf16 ; Wq (x 1/32), Wk -> transposed bf16
    cvt_xv<<<2048, 256, 0, stream>>>(x, Wv, xb, wvb);
    tr_w<<<512, 256, 0, stream>>>(Wq, Wk, wqT, wkT);

    // 2. d0: Wst = Wk^T-rows x Wq^T-rows (NT), 64 blocks @128²
    wst128<<<64, 256, 0, stream>>>(wkT, wqT, wst);

    // 3. d1: T-proj (128) + V-proj (128) @256² — exactly one machine round
    tv_proj<<<256, 512, 0, stream>>>(xb, wst, wvb, tb, vt);

    // 4. d2: causal scores S = T * x^T (544 blocks @128²)
    scores128<<<544, 256, 0, stream>>>(tb, xb, sc);

    // 5. causal softmax in place (wave-per-row)
    softmax_causal<<<2048, 256, 0, stream>>>(sc);

    // 6. out = P * V == P * Vt^T  (128²/BK=64 core, causal K-limit, paired)
    gemm128_pv<<<512, 256, 0, stream>>>(
        sc, S, (long long)S * S, vt, 8192, S, out, 1024, (long long)S * 1024, S);
}

// Round 13
// 137.424 us; speedup vs baseline: 1.1639x; 1.0538x over previous
//
#include <hip/hip_runtime.h>
#include <hip/hip_bf16.h>
#include <stdint.h>

typedef __attribute__((ext_vector_type(8))) short bf16x8;
typedef __attribute__((ext_vector_type(4))) float f32x4;

__device__ __forceinline__ float bf2f(unsigned short u) {
    union { unsigned int i; float f; } z; z.i = ((unsigned int)u) << 16; return z.f;
}
__device__ __forceinline__ unsigned short f2bf(float f) {
    union { float f; unsigned int i; } z; z.f = f;
    unsigned int x = z.i;
    unsigned int r = x + 0x7fffu + ((x >> 16) & 1u);
    return (unsigned short)(r >> 16);
}

typedef const __attribute__((address_space(1))) unsigned int* gp_t;
typedef __attribute__((address_space(3))) unsigned int* lp_t;

__device__ __forceinline__ void gload_lds16(const void* g, void* l) {
    __builtin_amdgcn_global_load_lds((gp_t)g, (lp_t)l, 16, 0, 0);
}

// bijective XCD-aware remap (m204 form) on a linear block id
__device__ __forceinline__ int xcd_remap(int orig, int nwg) {
    const int q = nwg >> 3, r = nwg & 7;
    const int xcd = orig & 7, pos = orig >> 3;
    return (xcd < r ? xcd * (q + 1) : r * (q + 1) + (xcd - r) * q) + pos;
}

// ======== merged conversions: {x,Wv -> bf16} + {Wq*1/32, Wk -> transposed} ==
// ids 0..2047: grid-stride float4 convert of x (xb) and Wv (wvb).
// ids 2048..2559: 64x64 LDS transpose tiles of Wq (scaled) / Wk.
__global__ __launch_bounds__(256) void cvt_tr(
    const float* __restrict__ x, const float* __restrict__ wq,
    const float* __restrict__ wk, const float* __restrict__ wv,
    unsigned short* __restrict__ xb, unsigned short* __restrict__ wvb,
    unsigned short* __restrict__ wqT, unsigned short* __restrict__ wkT) {
    const int id = blockIdx.x;
    if (id < 2048) {
        const int NX = 1 << 21;          // 8192*1024/4
        const int DD4 = 1 << 18;         // 1024*1024/4
        const int total = NX + DD4;
        int i = id * 256 + threadIdx.x;
        const int stride = 2048 * 256;
        for (; i < total; i += stride) {
            float4 v = (i < NX) ? reinterpret_cast<const float4*>(x)[i]
                                : reinterpret_cast<const float4*>(wv)[i - NX];
            ushort4 u;
            u.x = f2bf(v.x); u.y = f2bf(v.y); u.z = f2bf(v.z); u.w = f2bf(v.w);
            if (i < NX) reinterpret_cast<ushort4*>(xb)[i] = u;
            else        reinterpret_cast<ushort4*>(wvb)[i - NX] = u;
        }
    } else {
        const int id2 = id - 2048;           // 512 = 2 * 256 tiles
        const int m = id2 >> 8;              // 0: Wq, 1: Wk
        const int t = id2 & 255;
        const int tr = t >> 4, tc = t & 15;  // tile coords in src
        const float* src = m ? wk : wq;
        unsigned short* dst = m ? wkT : wqT;
        const float scale = m ? 1.0f : 0.03125f;

        __shared__ unsigned short tile[64][65];   // [src col][src row]
        const int tid = threadIdx.x;
        const int r0 = tid >> 4;             // 0..15
        const int c4 = tid & 15;             // float4 index within 64 cols
        #pragma unroll
        for (int p = 0; p < 4; ++p) {
            const int r = p * 16 + r0;
            float4 v = reinterpret_cast<const float4*>(
                src + (size_t)(tr * 64 + r) * 1024 + tc * 64)[c4];
            tile[c4 * 4 + 0][r] = f2bf(v.x * scale);
            tile[c4 * 4 + 1][r] = f2bf(v.y * scale);
            tile[c4 * 4 + 2][r] = f2bf(v.z * scale);
            tile[c4 * 4 + 3][r] = f2bf(v.w * scale);
        }
        __syncthreads();
        const int cr = tid >> 2;             // out-row within tile (src col)
        const int q4 = tid & 3;
        #pragma unroll
        for (int p = 0; p < 4; ++p) {
            const int off = (q4 * 4 + p) * 4;
            ushort4 u;
            u.x = tile[cr][off + 0]; u.y = tile[cr][off + 1];
            u.z = tile[cr][off + 2]; u.w = tile[cr][off + 3];
            *reinterpret_cast<ushort4*>(dst + (size_t)(tc * 64 + cr) * 1024 + tr * 64 + off) = u;
        }
    }
}

#define MFMA(a, b, c) __builtin_amdgcn_mfma_f32_16x16x32_bf16(a, b, c, 0, 0, 0)
#define SB() __builtin_amdgcn_sched_barrier(0)
#define BAR() __builtin_amdgcn_s_barrier()
#define LGKM0() asm volatile("s_waitcnt lgkmcnt(0)" ::: "memory")

// ======== 256x256 4-phase pipelined NT GEMM core (K=1024, lda=ldb=1024) ====
__device__ __forceinline__ void gemm256_core(
    const unsigned short* __restrict__ Ab,
    const unsigned short* __restrict__ Bb,
    int m0, int n0,
    unsigned short (&As)[2][256 * 64], unsigned short (&Bs)[2][256 * 64],
    f32x4 (&acc)[8][4])
{
    constexpr int LD = 1024, NK = 16;
    const int tid = threadIdx.x;
    const int l = tid & 63, w = tid >> 6;
    const int wr = w >> 2, wc = w & 3;

    const int srow = w * 8 + (l >> 3);
    const int scol = ((l & 7) ^ (l >> 3)) * 8;
    const size_t ldst = (size_t)w * 1024 + (size_t)l * 16;

    auto stageA = [&](int t, int h, int b) {
        const unsigned short* src = Ab + (size_t)(m0 + h * 128 + srow) * LD + t * 64 + scol;
        char* dst = (char*)&As[b][0] + h * 16384 + ldst;
        gload_lds16(src, dst);
        gload_lds16(src + (size_t)64 * LD, dst + 8192);
    };
    auto stageB = [&](int t, int h, int b) {
        const unsigned short* src = Bb + (size_t)(n0 + h * 128 + srow) * LD + t * 64 + scol;
        char* dst = (char*)&Bs[b][0] + h * 16384 + ldst;
        gload_lds16(src, dst);
        gload_lds16(src + (size_t)64 * LD, dst + 8192);
    };

    const int l15 = l & 15, l7 = l & 7;
    const int s0 = (((l >> 4) ^ l7) * 16);
    const int s1 = ((((l >> 4) + 4) ^ l7) * 16);

    bf16x8 Af[4][2], Bf0[2][2], Bf1[2][2];

    stageA(0, 0, 0); stageA(0, 1, 0); stageB(0, 0, 0); stageB(0, 1, 0);
    stageB(1, 0, 1); stageB(1, 1, 1);
    asm volatile("s_waitcnt vmcnt(4)" ::: "memory");
    SB(); BAR(); SB();

    for (int t = 0; t < NK; ++t) {
        const int b = t & 1, bn = b ^ 1;
        const char* ab = (const char*)&As[b][0] + (wr * 128 + l15) * 128;
        const char* bb = (const char*)&Bs[b][0] + (wc * 64 + l15) * 128;

        // P1: Q(0,0); stage A0(t+1)
        #pragma unroll
        for (int mi = 0; mi < 4; ++mi) {
            Af[mi][0] = *(const bf16x8*)(ab + mi * 2048 + s0);
            Af[mi][1] = *(const bf16x8*)(ab + mi * 2048 + s1);
        }
        #pragma unroll
        for (int ni = 0; ni < 2; ++ni) {
            Bf0[ni][0] = *(const bf16x8*)(bb + ni * 2048 + s0);
            Bf0[ni][1] = *(const bf16x8*)(bb + ni * 2048 + s1);
        }
        if (t + 1 < NK) stageA(t + 1, 0, bn);
        BAR(); LGKM0(); SB();
        __builtin_amdgcn_s_setprio(1);
        #pragma unroll
        for (int mi = 0; mi < 4; ++mi)
            #pragma unroll
            for (int ni = 0; ni < 2; ++ni) {
                acc[mi][ni] = MFMA(Af[mi][0], Bf0[ni][0], acc[mi][ni]);
                acc[mi][ni] = MFMA(Af[mi][1], Bf0[ni][1], acc[mi][ni]);
            }
        __builtin_amdgcn_s_setprio(0);
        SB(); BAR(); SB();

        // P2: Q(0,1); stage A1(t+1)
        #pragma unroll
        for (int ni = 0; ni < 2; ++ni) {
            Bf1[ni][0] = *(const bf16x8*)(bb + 4096 + ni * 2048 + s0);
            Bf1[ni][1] = *(const bf16x8*)(bb + 4096 + ni * 2048 + s1);
        }
        if (t + 1 < NK) stageA(t + 1, 1, bn);
        BAR(); LGKM0(); SB();
        __builtin_amdgcn_s_setprio(1);
        #pragma unroll
        for (int mi = 0; mi < 4; ++mi)
            #pragma unroll
            for (int ni = 0; ni < 2; ++ni) {
                acc[mi][2 + ni] = MFMA(Af[mi][0], Bf1[ni][0], acc[mi][2 + ni]);
                acc[mi][2 + ni] = MFMA(Af[mi][1], Bf1[ni][1], acc[mi][2 + ni]);
            }
        __builtin_amdgcn_s_setprio(0);
        SB(); BAR(); SB();

        // P3: Q(1,1); reads A qm1; stage B0(t+2) into b
        #pragma unroll
        for (int mi = 0; mi < 4; ++mi) {
            Af[mi][0] = *(const bf16x8*)(ab + 8192 + mi * 2048 + s0);
            Af[mi][1] = *(const bf16x8*)(ab + 8192 + mi * 2048 + s1);
        }
        if (t + 2 < NK) stageB(t + 2, 0, b);
        BAR(); LGKM0(); SB();
        __builtin_amdgcn_s_setprio(1);
        #pragma unroll
        for (int mi = 0; mi < 4; ++mi)
            #pragma unroll
            for (int ni = 0; ni < 2; ++ni) {
                acc[4 + mi][2 + ni] = MFMA(Af[mi][0], Bf1[ni][0], acc[4 + mi][2 + ni]);
                acc[4 + mi][2 + ni] = MFMA(Af[mi][1], Bf1[ni][1], acc[4 + mi][2 + ni]);
            }
        __builtin_amdgcn_s_setprio(0);
        SB(); BAR(); SB();

        // P4: Q(1,0); no reads; stage B1(t+2)
        if (t + 2 < NK) stageB(t + 2, 1, b);
        BAR(); SB();
        __builtin_amdgcn_s_setprio(1);
        #pragma unroll
        for (int mi = 0; mi < 4; ++mi)
            #pragma unroll
            for (int ni = 0; ni < 2; ++ni) {
                acc[4 + mi][ni] = MFMA(Af[mi][0], Bf0[ni][0], acc[4 + mi][ni]);
                acc[4 + mi][ni] = MFMA(Af[mi][1], Bf0[ni][1], acc[4 + mi][ni]);
            }
        __builtin_amdgcn_s_setprio(0);
        if (t + 2 < NK) {
            asm volatile("s_waitcnt vmcnt(4)" ::: "memory");
        } else if (t + 1 < NK) {
            asm volatile("s_waitcnt vmcnt(0)" ::: "memory");
        }
        SB(); BAR(); SB();
    }
}

// ======== d1: T-proj (128) + Vt-proj (128) @256², 1 round, all coalesced ===
// Roles interleave within each XCD: slot parity (orig>>3)&1.
//   T : tb[s][j] = sum_d xb[s][d]  wst[j][d]   (A=xb M=8192, B=wst N=1024)
//   Vt: vt[o][s] = sum_d wvb[o][d] xb[s][d]    (A=wvb M=1024, B=xb N=8192)
// Both epilogues are the standard coalesced row-major store — no scatter.
__global__ __launch_bounds__(512, 2) void tv_proj(
    const unsigned short* __restrict__ xb, const unsigned short* __restrict__ wst,
    const unsigned short* __restrict__ wvb,
    unsigned short* __restrict__ tb, unsigned short* __restrict__ vt)
{
    const int j = blockIdx.x;
    const int xcd = j & 7, slot = j >> 3;
    const int role = slot & 1;
    const int id_r = xcd * 16 + (slot >> 1);   // 0..127 within role

    __shared__ unsigned short As[2][256 * 64];
    __shared__ unsigned short Bs[2][256 * 64];
    f32x4 acc[8][4] = {};

    const int tid = threadIdx.x;
    const int l = tid & 63, w = tid >> 6;
    const int wr = w >> 2, wc = w & 3;
    const int crow = (l >> 4) * 4, ccol = l & 15;

    if (role == 0) {
        // T-projection; per-XCD: same nt, contiguous mt (shares wst panel)
        const int mt = id_r & 31, nt = id_r >> 5;      // nt 0..3
        const int m0 = mt * 256, n0 = nt * 256;
        gemm256_core(xb, wst, m0, n0, As, Bs, acc);
        #pragma unroll
        for (int mi = 0; mi < 8; ++mi)
            #pragma unroll
            for (int ni = 0; ni < 4; ++ni) {
                const size_t rbase = (size_t)(m0 + wr * 128 + mi * 16 + crow);
                const size_t cg = (size_t)(n0 + wc * 64 + ni * 16 + ccol);
                #pragma unroll
                for (int r = 0; r < 4; ++r)
                    tb[(rbase + r) * 1024 + cg] = f2bf(acc[mi][ni][r]);
            }
    } else {
        // Vt-projection: native orientation, coalesced row stores
        const int mt = id_r & 3, nt = id_r >> 2;       // mt 0..3, nt 0..31
        const int m0 = mt * 256, n0 = nt * 256;
        gemm256_core(wvb, xb, m0, n0, As, Bs, acc);
        #pragma unroll
        for (int mi = 0; mi < 8; ++mi)
            #pragma unroll
            for (int ni = 0; ni < 4; ++ni) {
                const size_t rbase = (size_t)(m0 + wr * 128 + mi * 16 + crow);
                const size_t cg = (size_t)(n0 + wc * 64 + ni * 16 + ccol);
                #pragma unroll
                for (int r = 0; r < 4; ++r)
                    vt[(rbase + r) * 8192 + cg] = f2bf(acc[mi][ni][r]);
            }
    }
}

// ======== 128x128 BK=64 core, counted-vmcnt 2-deep pipeline ========
__device__ __forceinline__ void gemm128_core64(
    const unsigned short* __restrict__ Ab, int lda,
    const unsigned short* __restrict__ Bb, int ldb,
    int m0, int n0, int nk,
    unsigned short (&As)[2][128 * 64], unsigned short (&Bs)[2][128 * 64],
    f32x4 (&acc)[4][4])
{
    const int tid = threadIdx.x;
    const int l = tid & 63, w = tid >> 6;
    const int wr = w >> 1, wc = w & 1;
    const int l15 = l & 15;

    const int srow = w * 8 + (l >> 3);
    const int scol = ((l & 7) ^ (l >> 3)) * 8;     // pre-swizzled source col
    const size_t ldst = (size_t)w * 1024 + (size_t)l * 16;

    auto stage = [&](int t, int b) {
        const int k0 = t * 64;
        #pragma unroll
        for (int i = 0; i < 4; ++i) {
            gload_lds16(Ab + (size_t)(m0 + i * 32 + srow) * lda + k0 + scol,
                        (char*)&As[b][0] + i * 4096 + ldst);
            gload_lds16(Bb + (size_t)(n0 + i * 32 + srow) * ldb + k0 + scol,
                        (char*)&Bs[b][0] + i * 4096 + ldst);
        }
    };

    const int s0 = (((l >> 4) ^ (l & 7)) * 16);
    const int s1 = ((((l >> 4) + 4) ^ (l & 7)) * 16);

    stage(0, 0);
    if (nk > 1) {
        stage(1, 1);
        asm volatile("s_waitcnt vmcnt(8)" ::: "memory");
    } else {
        asm volatile("s_waitcnt vmcnt(0)" ::: "memory");
    }
    SB(); BAR(); SB();

    for (int t = 0; t < nk; ++t) {
        const int b = t & 1;
        const char* ab = (const char*)&As[b][0] + (wr * 64 + l15) * 128;
        const char* bb = (const char*)&Bs[b][0] + (wc * 64 + l15) * 128;
        bf16x8 af[4][2], bfr[4][2];
        #pragma unroll
        for (int m = 0; m < 4; ++m) {
            af[m][0] = *(const bf16x8*)(ab + m * 2048 + s0);
            af[m][1] = *(const bf16x8*)(ab + m * 2048 + s1);
        }
        #pragma unroll
        for (int n = 0; n < 4; ++n) {
            bfr[n][0] = *(const bf16x8*)(bb + n * 2048 + s0);
            bfr[n][1] = *(const bf16x8*)(bb + n * 2048 + s1);
        }
        LGKM0(); SB();
        BAR(); SB();
        if (t + 2 < nk) stage(t + 2, b);

        __builtin_amdgcn_s_setprio(1);
        #pragma unroll
        for (int m = 0; m < 4; ++m)
            #pragma unroll
            for (int n = 0; n < 4; ++n) {
                acc[m][n] = MFMA(af[m][0], bfr[n][0], acc[m][n]);
                acc[m][n] = MFMA(af[m][1], bfr[n][1], acc[m][n]);
            }
        __builtin_amdgcn_s_setprio(0);

        if (t + 2 < nk) {
            asm volatile("s_waitcnt vmcnt(8)" ::: "memory");
        } else if (t + 1 < nk) {
            asm volatile("s_waitcnt vmcnt(0)" ::: "memory");
        }
        SB(); BAR(); SB();
    }
}

// ======== d0: Wst[d'][d] = sum_o Wk[o][d'] * Wq_scaled[o][d]  (64 blocks) ===
__global__ __launch_bounds__(256) void wst128(
    const unsigned short* __restrict__ wkT, const unsigned short* __restrict__ wqT,
    unsigned short* __restrict__ wst)
{
    const int wg = xcd_remap(blockIdx.x, 64);
    const int mt = wg & 7, nt = wg >> 3;
    const int m0 = mt * 128, n0 = nt * 128;

    __shared__ unsigned short As[2][128 * 64];
    __shared__ unsigned short Bs[2][128 * 64];
    f32x4 acc[4][4] = {};

    gemm128_core64(wkT, 1024, wqT, 1024, m0, n0, 16, As, Bs, acc);

    const int tid = threadIdx.x;
    const int l = tid & 63, w = tid >> 6;
    const int wr = w >> 1, wc = w & 1;
    const int crow = (l >> 4) * 4, ccol = l & 15;
    #pragma unroll
    for (int m = 0; m < 4; ++m)
        #pragma unroll
        for (int n = 0; n < 4; ++n) {
            const size_t rbase = (size_t)(m0 + wr * 64 + m * 16 + crow);
            const size_t cg = (size_t)(n0 + wc * 64 + n * 16 + ccol);
            #pragma unroll
            for (int r = 0; r < 4; ++r)
                wst[(rbase + r) * 1024 + cg] = f2bf(acc[m][n][r]);
        }
}

// ======== d2: causal scores S = T * x^T (544 blocks @128²) ========
__global__ __launch_bounds__(256) void scores128(
    const unsigned short* __restrict__ tb, const unsigned short* __restrict__ xb,
    unsigned short* __restrict__ sc)
{
    const int wg = xcd_remap(blockIdx.x, 544);

    __shared__ unsigned short As[2][128 * 64];
    __shared__ unsigned short Bs[2][128 * 64];
    f32x4 acc[4][4] = {};

    const int z = wg / 136, r = wg % 136;
    int mt = (int)((__builtin_sqrtf(8.f * r + 1.f) - 1.f) * 0.5f);
    while ((mt + 1) * (mt + 2) / 2 <= r) ++mt;
    while (mt * (mt + 1) / 2 > r) --mt;
    const int nt = r - mt * (mt + 1) / 2;
    const int m0 = mt * 128, n0 = nt * 128;
    const unsigned short* Ab = tb + (size_t)z * 2048 * 1024;
    const unsigned short* Bb = xb + (size_t)z * 2048 * 1024;
    gemm128_core64(Ab, 1024, Bb, 1024, m0, n0, 16, As, Bs, acc);

    const int tid = threadIdx.x;
    const int l = tid & 63, w = tid >> 6;
    const int wr = w >> 1, wc = w & 1;
    const int crow = (l >> 4) * 4, ccol = l & 15;
    unsigned short* C = sc + (size_t)z * 2048 * 2048;
    #pragma unroll
    for (int m = 0; m < 4; ++m)
        #pragma unroll
        for (int n = 0; n < 4; ++n) {
            const size_t rbase = (size_t)(m0 + wr * 64 + m * 16 + crow);
            const size_t cg = (size_t)(n0 + wc * 64 + n * 16 + ccol);
            #pragma unroll
            for (int r2 = 0; r2 < 4; ++r2)
                C[(rbase + r2) * 2048 + cg] = f2bf(acc[m][n][r2]);
        }
}

// ======== PV GEMM: 128x128 BK=64 core, fp32 out, causal K-limit ========
__global__ __launch_bounds__(256) void gemm128_pv(
    const unsigned short* __restrict__ A, int lda, long long sA,
    const unsigned short* __restrict__ B, int ldb, long long sB,
    float* __restrict__ C, int ldc, long long sC, int K)
{
    const int orig = blockIdx.x;
    const int h = orig >> 8;                   // 0/1 half
    const int c = xcd_remap(orig & 255, 256);
    const int z = c >> 6;
    const int rem = c & 63;
    const int nt = rem >> 3;
    const int j = rem & 7;
    const int mt = h ? (15 - j) : j;

    const unsigned short* Ab = A + (size_t)z * sA;
    const unsigned short* Bb = B + (size_t)z * sB;
    const int Keff = ((mt + 1) * 128 < K) ? (mt + 1) * 128 : K;
    const int nk = Keff >> 6;

    __shared__ unsigned short As[2][128 * 64];
    __shared__ unsigned short Bs[2][128 * 64];
    f32x4 acc[4][4] = {};

    gemm128_core64(Ab, lda, Bb, ldb, mt * 128, nt * 128, nk, As, Bs, acc);

    const int tid = threadIdx.x;
    const int l = tid & 63, w = tid >> 6;
    const int wr = w >> 1, wc = w & 1;
    const int crow = (l >> 4) * 4, ccol = l & 15;
    float* Cb = C + (size_t)z * sC;
    #pragma unroll
    for (int m = 0; m < 4; ++m)
        #pragma unroll
        for (int n = 0; n < 4; ++n) {
            const size_t rbase = (size_t)(mt * 128 + wr * 64 + m * 16 + crow);
            const size_t cg = (size_t)(nt * 128 + wc * 64 + n * 16 + ccol);
            #pragma unroll
            for (int r = 0; r < 4; ++r)
                Cb[(rbase + r) * ldc + cg] = acc[m][n][r];
        }
}

// ---------------- causal row softmax: wave-per-row, no LDS, no barriers -----
__global__ __launch_bounds__(256) void softmax_causal(unsigned short* __restrict__ P) {
    const int S = 2048;
    const int w = threadIdx.x >> 6, l = threadIdx.x & 63;
    const int gq = blockIdx.x * 4 + w;
    const int q = gq & (S - 1);
    unsigned short* row = P + (size_t)gq * S;
    const int wlim = ((q >> 7) + 1) << 7;
    const float NEG = -__builtin_huge_valf();

    float f[4][8];
    #pragma unroll
    for (int p = 0; p < 4; ++p) {
        const int c0 = p * 512 + l * 8;
        if (p * 512 <= q && c0 <= q) {
            uint4 rv = *reinterpret_cast<const uint4*>(row + c0);
            unsigned short us[8];
            us[0] = rv.x & 0xffff; us[1] = rv.x >> 16;
            us[2] = rv.y & 0xffff; us[3] = rv.y >> 16;
            us[4] = rv.z & 0xffff; us[5] = rv.z >> 16;
            us[6] = rv.w & 0xffff; us[7] = rv.w >> 16;
            #pragma unroll
            for (int i = 0; i < 8; ++i)
                f[p][i] = (c0 + i <= q) ? bf2f(us[i]) : NEG;
        } else {
            #pragma unroll
            for (int i = 0; i < 8; ++i) f[p][i] = NEG;
        }
    }

    float m = NEG;
    #pragma unroll
    for (int p = 0; p < 4; ++p)
        #pragma unroll
        for (int i = 0; i < 8; ++i) m = fmaxf(m, f[p][i]);
    #pragma unroll
    for (int o = 1; o < 64; o <<= 1) m = fmaxf(m, __shfl_xor(m, o));

    float s = 0.f;
    #pragma unroll
    for (int p = 0; p < 4; ++p)
        #pragma unroll
        for (int i = 0; i < 8; ++i) {
            f[p][i] = exp2f((f[p][i] - m) * 1.44269504f);   // -inf -> 0
            s += f[p][i];
        }
    #pragma unroll
    for (int o = 1; o < 64; o <<= 1) s += __shfl_xor(s, o);
    const float inv = 1.0f / s;

    #pragma unroll
    for (int p = 0; p < 4; ++p) {
        const int c0 = p * 512 + l * 8;
        if (p * 512 < wlim && c0 < wlim) {
            uint4 ov;
            ov.x = f2bf(f[p][0] * inv) | ((unsigned int)f2bf(f[p][1] * inv) << 16);
            ov.y = f2bf(f[p][2] * inv) | ((unsigned int)f2bf(f[p][3] * inv) << 16);
            ov.z = f2bf(f[p][4] * inv) | ((unsigned int)f2bf(f[p][5] * inv) << 16);
            ov.w = f2bf(f[p][6] * inv) | ((unsigned int)f2bf(f[p][7] * inv) << 16);
            *reinterpret_cast<uint4*>(row + c0) = ov;
        }
    }
}

extern "C" void kernel_launch(void* const* d_in, const int* in_sizes, int n_in,
                              void* d_out, int out_size, void* d_ws, size_t ws_size,
                              hipStream_t stream) {
    const float* x  = (const float*)d_in[0];
    const float* Wq = (const float*)d_in[1];
    const float* Wk = (const float*)d_in[2];
    const float* Wv = (const float*)d_in[3];
    float* out = (float*)d_out;

    const int S = 2048;

    char* ws = (char*)d_ws;
    unsigned short* xb  = (unsigned short*)(ws);                  // 16 MB [8192][1024]
    unsigned short* wvb = (unsigned short*)(ws + (16ull << 20));  //  2 MB
    unsigned short* wqT = (unsigned short*)(ws + (18ull << 20));  //  2 MB (Wq^T * 1/32)
    unsigned short* wkT = (unsigned short*)(ws + (20ull << 20));  //  2 MB (Wk^T)
    unsigned short* wst = (unsigned short*)(ws + (22ull << 20));  //  2 MB Wst[d'][d]
    unsigned short* tb  = (unsigned short*)(ws + (24ull << 20));  // 16 MB T=[8192][1024]
    unsigned short* vt  = (unsigned short*)(ws + (40ull << 20));  // 16 MB V^T [1024][8192]
    unsigned short* sc  = (unsigned short*)(ws + (56ull << 20));  // 32 MB [4][2048][2048]

    // 1. merged conversions (x,Wv -> bf16; Wq*1/32, Wk -> transposed bf16)
    cvt_tr<<<2560, 256, 0, stream>>>(x, Wq, Wk, Wv, xb, wvb, wqT, wkT);

    // 2. d0: Wst = Wk^T-rows x Wq^T-rows (NT), 64 blocks @128²
    wst128<<<64, 256, 0, stream>>>(wkT, wqT, wst);

    // 3. d1: T-proj (128) + Vt-proj (128) @256² — one round, coalesced stores
    tv_proj<<<256, 512, 0, stream>>>(xb, wst, wvb, tb, vt);

    // 4. d2: causal scores S = T * x^T (544 blocks @128²)
    scores128<<<544, 256, 0, stream>>>(tb, xb, sc);

    // 5. causal softmax in place (wave-per-row)
    softmax_causal<<<2048, 256, 0, stream>>>(sc);

    // 6. out = P * V == P * Vt^T  (128²/BK=64 core, causal K-limit, paired)
    gemm128_pv<<<512, 256, 0, stream>>>(
        sc, S, (long long)S * S, vt, 8192, S, out, 1024, (long long)S * 1024, S);
}